// Round 1
// baseline (1038.960 us; speedup 1.0000x reference)
//
#include <hip/hip_runtime.h>
#include <math.h>

#define DI 384   // d_inner
#define LSEQ 4096

__device__ __forceinline__ int trf(int l) { return ((l & 63) << 6) | (l >> 6); }
__device__ __forceinline__ int mapk(int k, int l) {
  if (k == 0) return l;
  if (k == 1) return trf(l);
  if (k == 2) return 4095 - l;
  return trf(4095 - l);
}
__device__ __forceinline__ float gelu_f(float x) {
  return 0.5f * x * (1.0f + erff(x * 0.7071067811865475f));
}
__device__ __forceinline__ float softplus_f(float x) {
  return (x > 20.0f) ? x : log1pf(expf(x));
}

// ---- in_proj GEMM: x[8192,192] @ w[768,192]^T -> xi_raw[8192,384], z_gelu[8192,384]
__global__ __launch_bounds__(256) void k_inproj(const float* __restrict__ x,
                                                const float* __restrict__ w,
                                                float* __restrict__ xi_raw,
                                                float* __restrict__ zg) {
  const int K = 192;
  __shared__ float As[16][65];
  __shared__ float Ws[16][65];
  int tid = threadIdx.x;
  int tx = tid & 15, ty = tid >> 4;
  int m0 = blockIdx.y * 64, n0 = blockIdx.x * 64;
  float acc[4][4] = {};
  for (int k0 = 0; k0 < K; k0 += 16) {
#pragma unroll
    for (int t = 0; t < 4; ++t) {
      int idx = tid + t * 256;
      int rr = idx >> 4, cc = idx & 15;
      As[cc][rr] = x[(size_t)(m0 + rr) * K + (k0 + cc)];
      Ws[cc][rr] = w[(size_t)(n0 + rr) * K + (k0 + cc)];
    }
    __syncthreads();
#pragma unroll
    for (int kk = 0; kk < 16; ++kk) {
      float a[4], bb[4];
#pragma unroll
      for (int i = 0; i < 4; ++i) a[i] = As[kk][ty + 16 * i];
#pragma unroll
      for (int j = 0; j < 4; ++j) bb[j] = Ws[kk][tx + 16 * j];
#pragma unroll
      for (int i = 0; i < 4; ++i)
#pragma unroll
        for (int j = 0; j < 4; ++j) acc[i][j] += a[i] * bb[j];
    }
    __syncthreads();
  }
#pragma unroll
  for (int i = 0; i < 4; ++i) {
    int m = m0 + ty + 16 * i;
#pragma unroll
    for (int j = 0; j < 4; ++j) {
      int n = n0 + tx + 16 * j;
      float v = acc[i][j];
      if (n < DI) xi_raw[(size_t)m * DI + n] = v;
      else zg[(size_t)m * DI + (n - DI)] = gelu_f(v);
    }
  }
}

// ---- depthwise 3x3 conv + bias + gelu
__global__ __launch_bounds__(256) void k_conv(const float* __restrict__ xin,
                                              const float* __restrict__ cw,
                                              const float* __restrict__ cb,
                                              float* __restrict__ xo) {
  int idx = blockIdx.x * 256 + threadIdx.x;  // over 2*4096*384
  int c = idx % DI;
  int lf = idx / DI;
  int b = lf >> 12;
  int l = lf & 4095;
  int h = l >> 6, w = l & 63;
  float acc = cb[c];
#pragma unroll
  for (int dh = -1; dh <= 1; ++dh) {
    int hh = h + dh;
    if ((unsigned)hh >= 64u) continue;
#pragma unroll
    for (int dw = -1; dw <= 1; ++dw) {
      int ww = w + dw;
      if ((unsigned)ww >= 64u) continue;
      acc += xin[((size_t)((b << 12) | (hh << 6) | ww)) * DI + c] *
             cw[c * 9 + (dh + 1) * 3 + (dw + 1)];
    }
  }
  xo[(size_t)idx] = gelu_f(acc);
}

// ---- x_proj GEMM per direction (gathered rows): xi[.,384] @ wk[140,384]^T
__global__ __launch_bounds__(256) void k_xproj(const float* __restrict__ xi,
                                               const float* __restrict__ w,
                                               const float* __restrict__ dt_bias,
                                               float* __restrict__ dt_buf,
                                               float* __restrict__ Bs_buf,
                                               float* __restrict__ Cs_buf) {
  const int K = DI, N = 140;
  int kdir = blockIdx.z;
  __shared__ float As[16][65];
  __shared__ float Ws[16][65];
  __shared__ int rowbase[64];
  int tid = threadIdx.x;
  int tx = tid & 15, ty = tid >> 4;
  int m0 = blockIdx.y * 64, n0 = blockIdx.x * 64;
  if (tid < 64) {
    int m = m0 + tid;
    int b = m >> 12, l = m & 4095;
    rowbase[tid] = (b << 12) + mapk(kdir, l);
  }
  const float* wk = w + (size_t)kdir * N * K;
  float acc[4][4] = {};
  __syncthreads();
  for (int k0 = 0; k0 < K; k0 += 16) {
#pragma unroll
    for (int t = 0; t < 4; ++t) {
      int idx = tid + t * 256;
      int rr = idx >> 4, cc = idx & 15;
      As[cc][rr] = xi[(size_t)rowbase[rr] * DI + (k0 + cc)];
      int n = n0 + rr;
      Ws[cc][rr] = (n < N) ? wk[(size_t)n * K + (k0 + cc)] : 0.0f;
    }
    __syncthreads();
#pragma unroll
    for (int kk = 0; kk < 16; ++kk) {
      float a[4], bb[4];
#pragma unroll
      for (int i = 0; i < 4; ++i) a[i] = As[kk][ty + 16 * i];
#pragma unroll
      for (int j = 0; j < 4; ++j) bb[j] = Ws[kk][tx + 16 * j];
#pragma unroll
      for (int i = 0; i < 4; ++i)
#pragma unroll
        for (int j = 0; j < 4; ++j) acc[i][j] += a[i] * bb[j];
    }
    __syncthreads();
  }
#pragma unroll
  for (int i = 0; i < 4; ++i) {
    int m = m0 + ty + 16 * i;
    int b = m >> 12, l = m & 4095;
#pragma unroll
    for (int j = 0; j < 4; ++j) {
      int n = n0 + tx + 16 * j;
      if (n >= N) continue;
      float v = acc[i][j];
      if (n < 12) {
        dt_buf[(((size_t)(b * 48 + kdir * 12 + n)) << 12) + l] =
            softplus_f(v + dt_bias[kdir * 12 + n]);
      } else if (n < 76) {
        Bs_buf[(((size_t)((b * 4 + kdir) << 12)) + l) * 64 + (n - 12)] = v;
      } else {
        Cs_buf[(((size_t)((b * 4 + kdir) << 12)) + l) * 64 + (n - 76)] = v;
      }
    }
  }
}

// ---- D1: per-chunk states[p,n] = sum_q B[q,n]*exp(Ac[63]-Ac[q])*x[q,p]*dt[q]
__global__ __launch_bounds__(256) void k_states(const float* __restrict__ xi,
                                                const float* __restrict__ dt_buf,
                                                const float* __restrict__ Bs_buf,
                                                const float* __restrict__ A_logs,
                                                float* __restrict__ states,
                                                float* __restrict__ cdec) {
  int c = blockIdx.x, h = blockIdx.y, b = blockIdx.z;
  int k = h / 12, r = h % 12;
  __shared__ float Bsh[64][65];
  __shared__ float xw[64][33];
  __shared__ float dts[64];
  __shared__ float dls[64];
  int tid = threadIdx.x;
  if (tid < 64) {
    float dtv = dt_buf[(((size_t)(b * 48 + h)) << 12) + c * 64 + tid];
    float Ah = -expf(A_logs[h]);
    float v = dtv * Ah;
#pragma unroll
    for (int off = 1; off < 64; off <<= 1) {
      float u = __shfl_up(v, off, 64);
      if (tid >= off) v += u;
    }
    float alast = __shfl(v, 63, 64);
    dts[tid] = dtv;
    dls[tid] = expf(alast - v);
    if (tid == 0) cdec[(b * 48 + h) * 64 + c] = expf(alast);
  }
  const float* Bp = Bs_buf + (((size_t)((b * 4 + k) << 12)) + c * 64) * 64;
  for (int t = tid; t < 4096; t += 256) Bsh[t >> 6][t & 63] = Bp[t];
  __syncthreads();
  for (int t = tid; t < 2048; t += 256) {
    int q = t >> 5, p = t & 31;
    int l = mapk(k, c * 64 + q);
    float xvv = xi[((size_t)((b << 12) + l)) * DI + r * 32 + p];
    xw[q][p] = xvv * dts[q] * dls[q];
  }
  __syncthreads();
  int n = tid & 63, pr = tid >> 6;
  float accv[8];
#pragma unroll
  for (int pp = 0; pp < 8; ++pp) accv[pp] = 0.0f;
  for (int q = 0; q < 64; ++q) {
    float bv = Bsh[q][n];
#pragma unroll
    for (int pp = 0; pp < 8; ++pp) accv[pp] += bv * xw[q][pr + pp * 4];
  }
  size_t base = ((size_t)(b * 48 + h) * 64 + c) * 2048;
#pragma unroll
  for (int pp = 0; pp < 8; ++pp) states[base + (pr + pp * 4) * 64 + n] = accv[pp];
}

// ---- D2: inter-chunk scan, in place: states[c] <- prev_state (exclusive)
__global__ __launch_bounds__(256) void k_scan(float* __restrict__ states,
                                              const float* __restrict__ cdec) {
  int bh = blockIdx.x;  // 0..95
  int tid = threadIdx.x;
  float S[8] = {0.f, 0.f, 0.f, 0.f, 0.f, 0.f, 0.f, 0.f};
  size_t base0 = (size_t)bh * 64 * 2048;
  for (int c = 0; c < 64; ++c) {
    float cd = cdec[bh * 64 + c];
    size_t base = base0 + (size_t)c * 2048;
#pragma unroll
    for (int j = 0; j < 8; ++j) {
      size_t idx = base + tid + j * 256;
      float tmp = states[idx];
      states[idx] = S[j];
      S[j] = cd * S[j] + tmp;
    }
  }
}

// ---- D3: Y = (tril(exp(dAc))*C.B^T*dt) @ x  +  exp(Ac)*C@prev^T  +  D*x
__global__ __launch_bounds__(256) void k_out(const float* __restrict__ xi,
                                             const float* __restrict__ dt_buf,
                                             const float* __restrict__ Bs_buf,
                                             const float* __restrict__ Cs_buf,
                                             const float* __restrict__ A_logs,
                                             const float* __restrict__ Ds,
                                             const float* __restrict__ prevs,
                                             float* __restrict__ ys) {
  int c = blockIdx.x, h = blockIdx.y, b = blockIdx.z;
  int k = h / 12, r = h % 12;
  __shared__ float Cl[64][65];
  __shared__ float G[64][65];
  __shared__ float uni[4224];  // union: Bl[64][64] | (xv[64][33] + pv[32][65])
  __shared__ float dts[64], acs[64], eas[64];
  float (*Bl)[64] = (float (*)[64])uni;
  float (*xv)[33] = (float (*)[33])uni;
  float (*pv)[65] = (float (*)[65])(uni + 2112);
  int tid = threadIdx.x;
  if (tid < 64) {
    float dtv = dt_buf[(((size_t)(b * 48 + h)) << 12) + c * 64 + tid];
    float Ah = -expf(A_logs[h]);
    float v = dtv * Ah;
#pragma unroll
    for (int off = 1; off < 64; off <<= 1) {
      float u = __shfl_up(v, off, 64);
      if (tid >= off) v += u;
    }
    dts[tid] = dtv;
    acs[tid] = v;
    eas[tid] = expf(v);
  }
  const float* Cp = Cs_buf + (((size_t)((b * 4 + k) << 12)) + c * 64) * 64;
  const float* Bp = Bs_buf + (((size_t)((b * 4 + k) << 12)) + c * 64) * 64;
  for (int t = tid; t < 4096; t += 256) {
    Cl[t >> 6][t & 63] = Cp[t];
    Bl[t >> 6][t & 63] = Bp[t];
  }
  __syncthreads();
  int q = tid & 63, sb = tid >> 6;
#pragma unroll
  for (int ss = 0; ss < 16; ++ss) {
    int s = sb + ss * 4;
    float g = 0.0f;
    if (q >= s) {
      float dot = 0.0f;
      for (int n = 0; n < 64; ++n) dot += Cl[q][n] * Bl[s][n];
      g = dot * expf(acs[q] - acs[s]) * dts[s];
    }
    G[q][s] = g;
  }
  __syncthreads();
  // overwrite Bl region with xv (raw x) and pv (prev state)
  for (int t = tid; t < 2048; t += 256) {
    int qq = t >> 5, p = t & 31;
    int l = mapk(k, c * 64 + qq);
    xv[qq][p] = xi[((size_t)((b << 12) + l)) * DI + r * 32 + p];
  }
  size_t pbase = ((size_t)(b * 48 + h) * 64 + c) * 2048;
  for (int t = tid; t < 2048; t += 256) pv[t >> 6][t & 63] = prevs[pbase + t];
  __syncthreads();
  int p = tid & 31, qg = tid >> 5;
  float dval = Ds[h * 32 + p];
#pragma unroll
  for (int qq = 0; qq < 8; ++qq) {
    int q2 = qg + qq * 8;
    float acc = 0.0f;
    for (int s2 = 0; s2 < 64; ++s2) acc += G[q2][s2] * xv[s2][p];
    float offv = 0.0f;
    for (int n = 0; n < 64; ++n) offv += Cl[q2][n] * pv[p][n];
    acc += eas[q2] * offv + dval * xv[q2][p];
    ys[(((size_t)((b * 4 + k) << 12)) + c * 64 + q2) * DI + r * 32 + p] = acc;
  }
}

// ---- combine 4 directions + LayerNorm + gate
__global__ __launch_bounds__(128) void k_ln(const float* __restrict__ ys,
                                            const float* __restrict__ zg,
                                            const float* __restrict__ gg,
                                            const float* __restrict__ bb,
                                            float* __restrict__ y2) {
  int row = blockIdx.x;
  int b = row >> 12, l = row & 4095;
  int l1 = trf(l);
  int l2 = 4095 - l;
  int l3 = 4095 - l1;
  int tid = threadIdx.x;
  float v[3];
  size_t base = ((size_t)(b * 4)) << 12;
#pragma unroll
  for (int j = 0; j < 3; ++j) {
    int d = tid + j * 128;
    v[j] = ys[(base + l) * DI + d] + ys[(base + 4096 + l1) * DI + d] +
           ys[(base + 8192 + l2) * DI + d] + ys[(base + 12288 + l3) * DI + d];
  }
  __shared__ float red[2];
  float s = v[0] + v[1] + v[2];
#pragma unroll
  for (int off = 32; off > 0; off >>= 1) s += __shfl_down(s, off, 64);
  if ((tid & 63) == 0) red[tid >> 6] = s;
  __syncthreads();
  float mu = (red[0] + red[1]) * (1.0f / 384.0f);
  __syncthreads();
  float d2 = 0.0f;
#pragma unroll
  for (int j = 0; j < 3; ++j) {
    float dd = v[j] - mu;
    d2 += dd * dd;
  }
#pragma unroll
  for (int off = 32; off > 0; off >>= 1) d2 += __shfl_down(d2, off, 64);
  if ((tid & 63) == 0) red[tid >> 6] = d2;
  __syncthreads();
  float rstd = rsqrtf((red[0] + red[1]) * (1.0f / 384.0f) + 1e-5f);
#pragma unroll
  for (int j = 0; j < 3; ++j) {
    int d = tid + j * 128;
    float yv = (v[j] - mu) * rstd * gg[d] + bb[d];
    y2[(size_t)row * DI + d] = yv * zg[(size_t)row * DI + d];
  }
}

// ---- out_proj GEMM: y2[8192,384] @ w[192,384]^T -> out[8192,192]
__global__ __launch_bounds__(256) void k_outproj(const float* __restrict__ a,
                                                 const float* __restrict__ w,
                                                 float* __restrict__ out) {
  const int K = 384, NO = 192;
  __shared__ float As[16][65];
  __shared__ float Ws[16][65];
  int tid = threadIdx.x;
  int tx = tid & 15, ty = tid >> 4;
  int m0 = blockIdx.y * 64, n0 = blockIdx.x * 64;
  float acc[4][4] = {};
  for (int k0 = 0; k0 < K; k0 += 16) {
#pragma unroll
    for (int t = 0; t < 4; ++t) {
      int idx = tid + t * 256;
      int rr = idx >> 4, cc = idx & 15;
      As[cc][rr] = a[(size_t)(m0 + rr) * K + (k0 + cc)];
      Ws[cc][rr] = w[(size_t)(n0 + rr) * K + (k0 + cc)];
    }
    __syncthreads();
#pragma unroll
    for (int kk = 0; kk < 16; ++kk) {
      float av[4], bb[4];
#pragma unroll
      for (int i = 0; i < 4; ++i) av[i] = As[kk][ty + 16 * i];
#pragma unroll
      for (int j = 0; j < 4; ++j) bb[j] = Ws[kk][tx + 16 * j];
#pragma unroll
      for (int i = 0; i < 4; ++i)
#pragma unroll
        for (int j = 0; j < 4; ++j) acc[i][j] += av[i] * bb[j];
    }
    __syncthreads();
  }
#pragma unroll
  for (int i = 0; i < 4; ++i) {
    int m = m0 + ty + 16 * i;
#pragma unroll
    for (int j = 0; j < 4; ++j) {
      int n = n0 + tx + 16 * j;
      out[(size_t)m * NO + n] = acc[i][j];
    }
  }
}

extern "C" void kernel_launch(void* const* d_in, const int* in_sizes, int n_in,
                              void* d_out, int out_size, void* d_ws, size_t ws_size,
                              hipStream_t stream) {
  const float* x = (const float*)d_in[0];
  const float* in_proj_w = (const float*)d_in[1];
  const float* conv_w = (const float*)d_in[2];
  const float* conv_b = (const float*)d_in[3];
  const float* x_proj_w = (const float*)d_in[4];
  const float* A_logs = (const float*)d_in[5];
  const float* Ds = (const float*)d_in[6];
  const float* dt_bias = (const float*)d_in[7];
  const float* out_norm_g = (const float*)d_in[8];
  const float* out_norm_b = (const float*)d_in[9];
  const float* out_proj_w = (const float*)d_in[10];
  float* out = (float*)d_out;

  float* ws = (float*)d_ws;
  float* xi_raw = ws;                       // 8192*384
  float* zg = xi_raw + 3145728;             // 8192*384
  float* xi = zg + 3145728;                 // 8192*384
  float* dt_buf = xi + 3145728;             // 2*48*4096
  float* Bs_buf = dt_buf + 393216;          // 2*4*4096*64
  float* Cs_buf = Bs_buf + 2097152;         // 2*4*4096*64
  float* states = Cs_buf + 2097152;         // 2*48*64*2048
  float* cdec = states + 12582912;          // 2*48*64
  float* ys = cdec + 6144;                  // 2*4*4096*384
  float* y2 = xi_raw;                       // alias (xi_raw dead after conv)

  k_inproj<<<dim3(12, 128), 256, 0, stream>>>(x, in_proj_w, xi_raw, zg);
  k_conv<<<dim3(12288), 256, 0, stream>>>(xi_raw, conv_w, conv_b, xi);
  k_xproj<<<dim3(3, 128, 4), 256, 0, stream>>>(xi, x_proj_w, dt_bias, dt_buf, Bs_buf, Cs_buf);
  k_states<<<dim3(64, 48, 2), 256, 0, stream>>>(xi, dt_buf, Bs_buf, A_logs, states, cdec);
  k_scan<<<dim3(96), 256, 0, stream>>>(states, cdec);
  k_out<<<dim3(64, 48, 2), 256, 0, stream>>>(xi, dt_buf, Bs_buf, Cs_buf, A_logs, Ds, states, ys);
  k_ln<<<dim3(8192), 128, 0, stream>>>(ys, zg, out_norm_g, out_norm_b, y2);
  k_outproj<<<dim3(3, 128), 256, 0, stream>>>(y2, out_proj_w, out);
}

// Round 2
// 587.653 us; speedup vs baseline: 1.7680x; 1.7680x over previous
//
#include <hip/hip_runtime.h>
#include <math.h>

#define DI 384   // d_inner

__device__ __forceinline__ int trf(int l) { return ((l & 63) << 6) | (l >> 6); }
__device__ __forceinline__ int mapk(int k, int l) {
  if (k == 0) return l;
  if (k == 1) return trf(l);
  if (k == 2) return 4095 - l;
  return trf(4095 - l);
}
__device__ __forceinline__ float gelu_f(float x) {
  return 0.5f * x * (1.0f + erff(x * 0.7071067811865475f));
}
__device__ __forceinline__ float softplus_f(float x) {
  return (x > 20.0f) ? x : log1pf(expf(x));
}

// ---- in_proj GEMM: x[8192,192] @ w[768,192]^T -> xi_raw[8192,384], z_gelu[8192,384]
__global__ __launch_bounds__(256) void k_inproj(const float* __restrict__ x,
                                                const float* __restrict__ w,
                                                float* __restrict__ xi_raw,
                                                float* __restrict__ zg) {
  const int K = 192;
  __shared__ __align__(16) float As[64][18];
  __shared__ __align__(16) float Ws[64][18];
  int tid = threadIdx.x;
  int tx = tid & 15, ty = tid >> 4;
  int m0 = blockIdx.y * 64, n0 = blockIdx.x * 64;
  float acc[4][4] = {};
  for (int k0 = 0; k0 < K; k0 += 16) {
#pragma unroll
    for (int t = 0; t < 4; ++t) {
      int idx = tid + t * 256;
      int rr = idx >> 4, cc = idx & 15;
      As[rr][cc] = x[(size_t)(m0 + rr) * K + (k0 + cc)];
      Ws[rr][cc] = w[(size_t)(n0 + rr) * K + (k0 + cc)];
    }
    __syncthreads();
#pragma unroll
    for (int kk = 0; kk < 16; kk += 2) {
      float2 a[4], bb[4];
#pragma unroll
      for (int i = 0; i < 4; ++i) a[i] = *(const float2*)&As[ty + 16 * i][kk];
#pragma unroll
      for (int j = 0; j < 4; ++j) bb[j] = *(const float2*)&Ws[tx + 16 * j][kk];
#pragma unroll
      for (int i = 0; i < 4; ++i)
#pragma unroll
        for (int j = 0; j < 4; ++j)
          acc[i][j] += a[i].x * bb[j].x + a[i].y * bb[j].y;
    }
    __syncthreads();
  }
#pragma unroll
  for (int i = 0; i < 4; ++i) {
    int m = m0 + ty + 16 * i;
#pragma unroll
    for (int j = 0; j < 4; ++j) {
      int n = n0 + tx + 16 * j;
      float v = acc[i][j];
      if (n < DI) xi_raw[(size_t)m * DI + n] = v;
      else zg[(size_t)m * DI + (n - DI)] = gelu_f(v);
    }
  }
}

// ---- depthwise 3x3 conv + bias + gelu
__global__ __launch_bounds__(256) void k_conv(const float* __restrict__ xin,
                                              const float* __restrict__ cw,
                                              const float* __restrict__ cb,
                                              float* __restrict__ xo) {
  int idx = blockIdx.x * 256 + threadIdx.x;  // over 2*4096*384
  int c = idx % DI;
  int lf = idx / DI;
  int b = lf >> 12;
  int l = lf & 4095;
  int h = l >> 6, w = l & 63;
  float acc = cb[c];
#pragma unroll
  for (int dh = -1; dh <= 1; ++dh) {
    int hh = h + dh;
    if ((unsigned)hh >= 64u) continue;
#pragma unroll
    for (int dw = -1; dw <= 1; ++dw) {
      int ww = w + dw;
      if ((unsigned)ww >= 64u) continue;
      acc += xin[((size_t)((b << 12) | (hh << 6) | ww)) * DI + c] *
             cw[c * 9 + (dh + 1) * 3 + (dw + 1)];
    }
  }
  xo[(size_t)idx] = gelu_f(acc);
}

// ---- x_proj GEMM per direction (gathered rows): xi[.,384] @ wk[140,384]^T
__global__ __launch_bounds__(256) void k_xproj(const float* __restrict__ xi,
                                               const float* __restrict__ w,
                                               const float* __restrict__ dt_bias,
                                               float* __restrict__ dt_buf,
                                               float* __restrict__ Bs_buf,
                                               float* __restrict__ Cs_buf) {
  const int K = DI, N = 140;
  int kdir = blockIdx.z;
  __shared__ __align__(16) float As[64][18];
  __shared__ __align__(16) float Ws[64][18];
  __shared__ int rowbase[64];
  int tid = threadIdx.x;
  int tx = tid & 15, ty = tid >> 4;
  int m0 = blockIdx.y * 64, n0 = blockIdx.x * 64;
  if (tid < 64) {
    int m = m0 + tid;
    int b = m >> 12, l = m & 4095;
    rowbase[tid] = (b << 12) + mapk(kdir, l);
  }
  const float* wk = w + (size_t)kdir * N * K;
  float acc[4][4] = {};
  __syncthreads();
  for (int k0 = 0; k0 < K; k0 += 16) {
#pragma unroll
    for (int t = 0; t < 4; ++t) {
      int idx = tid + t * 256;
      int rr = idx >> 4, cc = idx & 15;
      As[rr][cc] = xi[(size_t)rowbase[rr] * DI + (k0 + cc)];
      int n = n0 + rr;
      Ws[rr][cc] = (n < N) ? wk[(size_t)n * K + (k0 + cc)] : 0.0f;
    }
    __syncthreads();
#pragma unroll
    for (int kk = 0; kk < 16; kk += 2) {
      float2 a[4], bb[4];
#pragma unroll
      for (int i = 0; i < 4; ++i) a[i] = *(const float2*)&As[ty + 16 * i][kk];
#pragma unroll
      for (int j = 0; j < 4; ++j) bb[j] = *(const float2*)&Ws[tx + 16 * j][kk];
#pragma unroll
      for (int i = 0; i < 4; ++i)
#pragma unroll
        for (int j = 0; j < 4; ++j)
          acc[i][j] += a[i].x * bb[j].x + a[i].y * bb[j].y;
    }
    __syncthreads();
  }
#pragma unroll
  for (int i = 0; i < 4; ++i) {
    int m = m0 + ty + 16 * i;
    int b = m >> 12, l = m & 4095;
#pragma unroll
    for (int j = 0; j < 4; ++j) {
      int n = n0 + tx + 16 * j;
      if (n >= N) continue;
      float v = acc[i][j];
      if (n < 12) {
        dt_buf[(((size_t)(b * 48 + kdir * 12 + n)) << 12) + l] =
            softplus_f(v + dt_bias[kdir * 12 + n]);
      } else if (n < 76) {
        Bs_buf[(((size_t)((b * 4 + kdir) << 12)) + l) * 64 + (n - 12)] = v;
      } else {
        Cs_buf[(((size_t)((b * 4 + kdir) << 12)) + l) * 64 + (n - 76)] = v;
      }
    }
  }
}

// ---- D1: per (b,k,c): states_h[p,n] = sum_q B[q,n]*exp(Ac[63]-Ac[q])*dt[q]*x_h[q,p]
__global__ __launch_bounds__(256) void k_states(const float* __restrict__ xi,
                                                const float* __restrict__ dt_buf,
                                                const float* __restrict__ Bs_buf,
                                                const float* __restrict__ A_logs,
                                                float* __restrict__ states,
                                                float* __restrict__ cdec) {
  int c = blockIdx.x, k = blockIdx.y, b = blockIdx.z;
  __shared__ __align__(16) float Bt[64][66];   // [n][q]
  __shared__ __align__(16) float xwT[32][66];  // [p][q]
  __shared__ float dts[64], dls[64];
  int tid = threadIdx.x;
  int tx = tid & 15, ty = tid >> 4;
  const float* Bp = Bs_buf + (((size_t)((b * 4 + k) << 12)) + c * 64) * 64;
  for (int t = tid; t < 4096; t += 256) {
    int q = t >> 6, n = t & 63;
    Bt[n][q] = Bp[t];
  }
  for (int r = 0; r < 12; ++r) {
    int h = k * 12 + r;
    __syncthreads();  // xwT free (prev GEMM done); first iter: nothing
    if (tid < 64) {
      float dtv = dt_buf[(((size_t)(b * 48 + h)) << 12) + c * 64 + tid];
      float Ah = -expf(A_logs[h]);
      float v = dtv * Ah;
#pragma unroll
      for (int off = 1; off < 64; off <<= 1) {
        float u = __shfl_up(v, off, 64);
        if (tid >= off) v += u;
      }
      float alast = __shfl(v, 63, 64);
      dts[tid] = dtv;
      dls[tid] = expf(alast - v);
      if (tid == 0) cdec[(b * 48 + h) * 64 + c] = expf(alast);
    }
    __syncthreads();  // dts/dls ready
    for (int t = tid; t < 2048; t += 256) {
      int qq = t >> 5, p = t & 31;
      int l = mapk(k, c * 64 + qq);
      float xvv = xi[((size_t)((b << 12) + l)) * DI + r * 32 + p];
      xwT[p][qq] = xvv * dts[qq] * dls[qq];
    }
    __syncthreads();  // xwT ready (Bt ready since first barrier pair)
    float accS[2][4] = {};
#pragma unroll 4
    for (int q0 = 0; q0 < 64; q0 += 2) {
      float2 xw2[2], bt2[4];
#pragma unroll
      for (int i = 0; i < 2; ++i) xw2[i] = *(const float2*)&xwT[ty + 16 * i][q0];
#pragma unroll
      for (int j = 0; j < 4; ++j) bt2[j] = *(const float2*)&Bt[tx + 16 * j][q0];
#pragma unroll
      for (int i = 0; i < 2; ++i)
#pragma unroll
        for (int j = 0; j < 4; ++j)
          accS[i][j] += xw2[i].x * bt2[j].x + xw2[i].y * bt2[j].y;
    }
    size_t base = ((size_t)(b * 48 + h) * 64 + c) * 2048;
#pragma unroll
    for (int i = 0; i < 2; ++i)
#pragma unroll
      for (int j = 0; j < 4; ++j)
        states[base + (ty + 16 * i) * 64 + (tx + 16 * j)] = accS[i][j];
  }
}

// ---- D2: inter-chunk scan, in place: states[c] <- prev_state (exclusive)
__global__ __launch_bounds__(256) void k_scan(float* __restrict__ states,
                                              const float* __restrict__ cdec) {
  int j = blockIdx.x;   // 0..7
  int bh = blockIdx.y;  // 0..95
  int tid = threadIdx.x;
  size_t base0 = (size_t)bh * 64 * 2048 + j * 256 + tid;
  float S = 0.0f;
  float nxt = states[base0];
  for (int c = 0; c < 64; ++c) {
    float cd = cdec[bh * 64 + c];
    size_t idx = base0 + (size_t)c * 2048;
    float tmp = nxt;
    if (c < 63) nxt = states[idx + 2048];
    states[idx] = S;
    S = cd * S + tmp;
  }
}

// ---- D3: per (b,k,c): CB^T once (registers), then 12 heads:
//      Y = G_h @ x  +  exp(Ac)*(C @ prev_h^T)  +  D*x
__global__ __launch_bounds__(256) void k_out(const float* __restrict__ xi,
                                             const float* __restrict__ dt_buf,
                                             const float* __restrict__ Bs_buf,
                                             const float* __restrict__ Cs_buf,
                                             const float* __restrict__ A_logs,
                                             const float* __restrict__ Ds,
                                             const float* __restrict__ prevs,
                                             float* __restrict__ ys) {
  int c = blockIdx.x, k = blockIdx.y, b = blockIdx.z;
  __shared__ __align__(16) float Cl[64][66];   // [q][n]
  __shared__ __align__(16) float Gf[64][66];   // per-head G  [q][s]
  __shared__ __align__(16) float uni[4224];    // Bl[64][66] | xvT[32][66]+pv[32][66]
  __shared__ float acs_sh[64], dts_sh[64], eas_sh[64];
  float (*Bl)[66] = (float (*)[66])uni;
  float (*xvT)[66] = (float (*)[66])uni;            // [p][s] raw x
  float (*pv)[66] = (float (*)[66])(uni + 32 * 66); // [p][n] prev state
  int tid = threadIdx.x;
  int tx = tid & 15, ty = tid >> 4;
  const float* Cp = Cs_buf + (((size_t)((b * 4 + k) << 12)) + c * 64) * 64;
  const float* Bp = Bs_buf + (((size_t)((b * 4 + k) << 12)) + c * 64) * 64;
  for (int t = tid; t < 4096; t += 256) {
    int q = t >> 6, n = t & 63;
    Cl[q][n] = Cp[t];
    Bl[q][n] = Bp[t];
  }
  __syncthreads();
  // CB^T into registers: cbt[i][j] = sum_n C[ty+16i][n] * B[tx+16j][n]
  float cbt[4][4] = {};
#pragma unroll 4
  for (int n0 = 0; n0 < 64; n0 += 2) {
    float2 a[4], bb[4];
#pragma unroll
    for (int i = 0; i < 4; ++i) a[i] = *(const float2*)&Cl[ty + 16 * i][n0];
#pragma unroll
    for (int j = 0; j < 4; ++j) bb[j] = *(const float2*)&Bl[tx + 16 * j][n0];
#pragma unroll
    for (int i = 0; i < 4; ++i)
#pragma unroll
      for (int j = 0; j < 4; ++j)
        cbt[i][j] += a[i].x * bb[j].x + a[i].y * bb[j].y;
  }
  for (int r = 0; r < 12; ++r) {
    int h = k * 12 + r;
    __syncthreads();  // prev GEMM done reading Gf/xvT/pv; (iter 0: Bl reads done)
    if (tid < 64) {
      float dtv = dt_buf[(((size_t)(b * 48 + h)) << 12) + c * 64 + tid];
      float Ah = -expf(A_logs[h]);
      float v = dtv * Ah;
#pragma unroll
      for (int off = 1; off < 64; off <<= 1) {
        float u = __shfl_up(v, off, 64);
        if (tid >= off) v += u;
      }
      dts_sh[tid] = dtv;
      acs_sh[tid] = v;
      eas_sh[tid] = expf(v);
    }
    for (int t = tid; t < 2048; t += 256) {
      int s = t >> 5, p = t & 31;
      int l = mapk(k, c * 64 + s);
      xvT[p][s] = xi[((size_t)((b << 12) + l)) * DI + r * 32 + p];
    }
    size_t pbase = ((size_t)(b * 48 + h) * 64 + c) * 2048;
    for (int t = tid; t < 2048; t += 256) {
      int p = t >> 6, n = t & 63;
      pv[p][n] = prevs[pbase + t];
    }
    __syncthreads();  // acs/dts ready, xvT/pv loaded
    // Build G from register CBt
#pragma unroll
    for (int i = 0; i < 4; ++i) {
      int q = ty + 16 * i;
      float aq = acs_sh[q];
#pragma unroll
      for (int j = 0; j < 4; ++j) {
        int s = tx + 16 * j;
        float arg = fminf(aq - acs_sh[s], 0.0f);
        float g = (q >= s) ? cbt[i][j] * expf(arg) * dts_sh[s] : 0.0f;
        Gf[q][s] = g;
      }
    }
    __syncthreads();  // Gf ready
    float accD[4][2] = {};
    float accO[4][2] = {};
#pragma unroll 4
    for (int s0 = 0; s0 < 64; s0 += 2) {
      float2 g[4], cc[4], xx[2], vv[2];
#pragma unroll
      for (int i = 0; i < 4; ++i) {
        g[i] = *(const float2*)&Gf[ty + 16 * i][s0];
        cc[i] = *(const float2*)&Cl[ty + 16 * i][s0];
      }
#pragma unroll
      for (int j = 0; j < 2; ++j) {
        xx[j] = *(const float2*)&xvT[tx + 16 * j][s0];
        vv[j] = *(const float2*)&pv[tx + 16 * j][s0];
      }
#pragma unroll
      for (int i = 0; i < 4; ++i)
#pragma unroll
        for (int j = 0; j < 2; ++j) {
          accD[i][j] += g[i].x * xx[j].x + g[i].y * xx[j].y;
          accO[i][j] += cc[i].x * vv[j].x + cc[i].y * vv[j].y;
        }
    }
#pragma unroll
    for (int i = 0; i < 4; ++i) {
      int q = ty + 16 * i;
      float ea = eas_sh[q];
#pragma unroll
      for (int j = 0; j < 2; ++j) {
        int p = tx + 16 * j;
        float yv = accD[i][j] + ea * accO[i][j] + Ds[h * 32 + p] * xvT[p][q];
        ys[(((size_t)((b * 4 + k) << 12)) + c * 64 + q) * DI + r * 32 + p] = yv;
      }
    }
  }
}

// ---- combine 4 directions + LayerNorm + gate
__global__ __launch_bounds__(128) void k_ln(const float* __restrict__ ys,
                                            const float* __restrict__ zg,
                                            const float* __restrict__ gg,
                                            const float* __restrict__ bb,
                                            float* __restrict__ y2) {
  int row = blockIdx.x;
  int b = row >> 12, l = row & 4095;
  int l1 = trf(l);
  int l2 = 4095 - l;
  int l3 = 4095 - l1;
  int tid = threadIdx.x;
  float v[3];
  size_t base = ((size_t)(b * 4)) << 12;
#pragma unroll
  for (int j = 0; j < 3; ++j) {
    int d = tid + j * 128;
    v[j] = ys[(base + l) * DI + d] + ys[(base + 4096 + l1) * DI + d] +
           ys[(base + 8192 + l2) * DI + d] + ys[(base + 12288 + l3) * DI + d];
  }
  __shared__ float red[2];
  float s = v[0] + v[1] + v[2];
#pragma unroll
  for (int off = 32; off > 0; off >>= 1) s += __shfl_down(s, off, 64);
  if ((tid & 63) == 0) red[tid >> 6] = s;
  __syncthreads();
  float mu = (red[0] + red[1]) * (1.0f / 384.0f);
  __syncthreads();
  float d2 = 0.0f;
#pragma unroll
  for (int j = 0; j < 3; ++j) {
    float dd = v[j] - mu;
    d2 += dd * dd;
  }
#pragma unroll
  for (int off = 32; off > 0; off >>= 1) d2 += __shfl_down(d2, off, 64);
  if ((tid & 63) == 0) red[tid >> 6] = d2;
  __syncthreads();
  float rstd = rsqrtf((red[0] + red[1]) * (1.0f / 384.0f) + 1e-5f);
#pragma unroll
  for (int j = 0; j < 3; ++j) {
    int d = tid + j * 128;
    float yv = (v[j] - mu) * rstd * gg[d] + bb[d];
    y2[(size_t)row * DI + d] = yv * zg[(size_t)row * DI + d];
  }
}

// ---- out_proj GEMM: y2[8192,384] @ w[192,384]^T -> out[8192,192]
__global__ __launch_bounds__(256) void k_outproj(const float* __restrict__ a,
                                                 const float* __restrict__ w,
                                                 float* __restrict__ out) {
  const int K = 384, NO = 192;
  __shared__ __align__(16) float As[64][18];
  __shared__ __align__(16) float Ws[64][18];
  int tid = threadIdx.x;
  int tx = tid & 15, ty = tid >> 4;
  int m0 = blockIdx.y * 64, n0 = blockIdx.x * 64;
  float acc[4][4] = {};
  for (int k0 = 0; k0 < K; k0 += 16) {
#pragma unroll
    for (int t = 0; t < 4; ++t) {
      int idx = tid + t * 256;
      int rr = idx >> 4, cc = idx & 15;
      As[rr][cc] = a[(size_t)(m0 + rr) * K + (k0 + cc)];
      Ws[rr][cc] = w[(size_t)(n0 + rr) * K + (k0 + cc)];
    }
    __syncthreads();
#pragma unroll
    for (int kk = 0; kk < 16; kk += 2) {
      float2 av[4], bv[4];
#pragma unroll
      for (int i = 0; i < 4; ++i) av[i] = *(const float2*)&As[ty + 16 * i][kk];
#pragma unroll
      for (int j = 0; j < 4; ++j) bv[j] = *(const float2*)&Ws[tx + 16 * j][kk];
#pragma unroll
      for (int i = 0; i < 4; ++i)
#pragma unroll
        for (int j = 0; j < 4; ++j)
          acc[i][j] += av[i].x * bv[j].x + av[i].y * bv[j].y;
    }
    __syncthreads();
  }
#pragma unroll
  for (int i = 0; i < 4; ++i) {
    int m = m0 + ty + 16 * i;
#pragma unroll
    for (int j = 0; j < 4; ++j) {
      int n = n0 + tx + 16 * j;
      out[(size_t)m * NO + n] = acc[i][j];
    }
  }
}

extern "C" void kernel_launch(void* const* d_in, const int* in_sizes, int n_in,
                              void* d_out, int out_size, void* d_ws, size_t ws_size,
                              hipStream_t stream) {
  const float* x = (const float*)d_in[0];
  const float* in_proj_w = (const float*)d_in[1];
  const float* conv_w = (const float*)d_in[2];
  const float* conv_b = (const float*)d_in[3];
  const float* x_proj_w = (const float*)d_in[4];
  const float* A_logs = (const float*)d_in[5];
  const float* Ds = (const float*)d_in[6];
  const float* dt_bias = (const float*)d_in[7];
  const float* out_norm_g = (const float*)d_in[8];
  const float* out_norm_b = (const float*)d_in[9];
  const float* out_proj_w = (const float*)d_in[10];
  float* out = (float*)d_out;

  float* ws = (float*)d_ws;
  float* xi_raw = ws;                       // 8192*384
  float* zg = xi_raw + 3145728;             // 8192*384
  float* xi = zg + 3145728;                 // 8192*384
  float* dt_buf = xi + 3145728;             // 2*48*4096
  float* Bs_buf = dt_buf + 393216;          // 2*4*4096*64
  float* Cs_buf = Bs_buf + 2097152;         // 2*4*4096*64
  float* states = Cs_buf + 2097152;         // 2*48*64*2048
  float* cdec = states + 12582912;          // 2*48*64
  float* ys = cdec + 6144;                  // 2*4*4096*384
  float* y2 = xi_raw;                       // alias (xi_raw dead after conv)

  k_inproj<<<dim3(12, 128), 256, 0, stream>>>(x, in_proj_w, xi_raw, zg);
  k_conv<<<dim3(12288), 256, 0, stream>>>(xi_raw, conv_w, conv_b, xi);
  k_xproj<<<dim3(3, 128, 4), 256, 0, stream>>>(xi, x_proj_w, dt_bias, dt_buf, Bs_buf, Cs_buf);
  k_states<<<dim3(64, 4, 2), 256, 0, stream>>>(xi, dt_buf, Bs_buf, A_logs, states, cdec);
  k_scan<<<dim3(8, 96), 256, 0, stream>>>(states, cdec);
  k_out<<<dim3(64, 4, 2), 256, 0, stream>>>(xi, dt_buf, Bs_buf, Cs_buf, A_logs, Ds, states, ys);
  k_ln<<<dim3(8192), 128, 0, stream>>>(ys, zg, out_norm_g, out_norm_b, y2);
  k_outproj<<<dim3(3, 128), 256, 0, stream>>>(y2, out_proj_w, out);
}

// Round 3
// 439.987 us; speedup vs baseline: 2.3613x; 1.3356x over previous
//
#include <hip/hip_runtime.h>
#include <math.h>

#define DI 384   // d_inner

typedef __attribute__((ext_vector_type(8))) short bf8v;   // 8 bf16
typedef __attribute__((ext_vector_type(4))) float f4v;    // 4 fp32

__device__ __forceinline__ f4v mfma16(bf8v a, bf8v b, f4v c) {
  return __builtin_amdgcn_mfma_f32_16x16x32_bf16(a, b, c, 0, 0, 0);
}

__device__ __forceinline__ int trf(int l) { return ((l & 63) << 6) | (l >> 6); }
__device__ __forceinline__ int mapk(int k, int l) {
  if (k == 0) return l;
  if (k == 1) return trf(l);
  if (k == 2) return 4095 - l;
  return trf(4095 - l);
}
__device__ __forceinline__ float gelu_f(float x) {
  return 0.5f * x * (1.0f + erff(x * 0.7071067811865475f));
}
__device__ __forceinline__ float softplus_f(float x) {
  return (x > 20.0f) ? x : log1pf(expf(x));
}
__device__ __forceinline__ unsigned short f2bf(float f) {
  unsigned u = __float_as_uint(f);
  unsigned r = (u + 0x7fff + ((u >> 16) & 1)) >> 16;
  return (unsigned short)r;
}
__device__ __forceinline__ float bf2f(unsigned short h) {
  return __uint_as_float(((unsigned)h) << 16);
}
// element offset in a [R][64] u16 plane, XOR-swizzled per 8-elem block
__device__ __forceinline__ int swz(int row, int col) {
  return (row << 6) + ((((col >> 3) ^ (row & 7)) << 3) | (col & 7));
}
__device__ __forceinline__ int foff(int row, int cb) {
  return (row << 6) + ((cb ^ (row & 7)) << 3);
}

// ---- in_proj GEMM: x[8192,192] @ w[768,192]^T -> xi_raw[8192,384], z_gelu[8192,384]
__global__ __launch_bounds__(256) void k_inproj(const float* __restrict__ x,
                                                const float* __restrict__ w,
                                                float* __restrict__ xi_raw,
                                                float* __restrict__ zg) {
  const int K = 192;
  __shared__ __align__(16) float As[64][18];
  __shared__ __align__(16) float Ws[64][18];
  int tid = threadIdx.x;
  int tx = tid & 15, ty = tid >> 4;
  int m0 = blockIdx.y * 64, n0 = blockIdx.x * 64;
  float acc[4][4] = {};
  for (int k0 = 0; k0 < K; k0 += 16) {
#pragma unroll
    for (int t = 0; t < 4; ++t) {
      int idx = tid + t * 256;
      int rr = idx >> 4, cc = idx & 15;
      As[rr][cc] = x[(size_t)(m0 + rr) * K + (k0 + cc)];
      Ws[rr][cc] = w[(size_t)(n0 + rr) * K + (k0 + cc)];
    }
    __syncthreads();
#pragma unroll
    for (int kk = 0; kk < 16; kk += 2) {
      float2 a[4], bb[4];
#pragma unroll
      for (int i = 0; i < 4; ++i) a[i] = *(const float2*)&As[ty + 16 * i][kk];
#pragma unroll
      for (int j = 0; j < 4; ++j) bb[j] = *(const float2*)&Ws[tx + 16 * j][kk];
#pragma unroll
      for (int i = 0; i < 4; ++i)
#pragma unroll
        for (int j = 0; j < 4; ++j)
          acc[i][j] += a[i].x * bb[j].x + a[i].y * bb[j].y;
    }
    __syncthreads();
  }
#pragma unroll
  for (int i = 0; i < 4; ++i) {
    int m = m0 + ty + 16 * i;
#pragma unroll
    for (int j = 0; j < 4; ++j) {
      int n = n0 + tx + 16 * j;
      float v = acc[i][j];
      if (n < DI) xi_raw[(size_t)m * DI + n] = v;
      else zg[(size_t)m * DI + (n - DI)] = gelu_f(v);
    }
  }
}

// ---- depthwise 3x3 conv + bias + gelu
__global__ __launch_bounds__(256) void k_conv(const float* __restrict__ xin,
                                              const float* __restrict__ cw,
                                              const float* __restrict__ cb,
                                              float* __restrict__ xo) {
  int idx = blockIdx.x * 256 + threadIdx.x;  // over 2*4096*384
  int c = idx % DI;
  int lf = idx / DI;
  int b = lf >> 12;
  int l = lf & 4095;
  int h = l >> 6, w = l & 63;
  float acc = cb[c];
#pragma unroll
  for (int dh = -1; dh <= 1; ++dh) {
    int hh = h + dh;
    if ((unsigned)hh >= 64u) continue;
#pragma unroll
    for (int dw = -1; dw <= 1; ++dw) {
      int ww = w + dw;
      if ((unsigned)ww >= 64u) continue;
      acc += xin[((size_t)((b << 12) | (hh << 6) | ww)) * DI + c] *
             cw[c * 9 + (dh + 1) * 3 + (dw + 1)];
    }
  }
  xo[(size_t)idx] = gelu_f(acc);
}

// ---- x_proj GEMM per direction (gathered rows): xi[.,384] @ wk[140,384]^T
// writes dt (softplus'd, fp32) and B/C as bf16 hi/lo planes
__global__ __launch_bounds__(256) void k_xproj(const float* __restrict__ xi,
                                               const float* __restrict__ w,
                                               const float* __restrict__ dt_bias,
                                               float* __restrict__ dt_buf,
                                               unsigned short* __restrict__ Bhi,
                                               unsigned short* __restrict__ Blo,
                                               unsigned short* __restrict__ Chi,
                                               unsigned short* __restrict__ Clo) {
  const int K = DI, N = 140;
  int kdir = blockIdx.z;
  __shared__ __align__(16) float As[64][18];
  __shared__ __align__(16) float Ws[64][18];
  __shared__ int rowbase[64];
  int tid = threadIdx.x;
  int tx = tid & 15, ty = tid >> 4;
  int m0 = blockIdx.y * 64, n0 = blockIdx.x * 64;
  if (tid < 64) {
    int m = m0 + tid;
    int b = m >> 12, l = m & 4095;
    rowbase[tid] = (b << 12) + mapk(kdir, l);
  }
  const float* wk = w + (size_t)kdir * N * K;
  float acc[4][4] = {};
  __syncthreads();
  for (int k0 = 0; k0 < K; k0 += 16) {
#pragma unroll
    for (int t = 0; t < 4; ++t) {
      int idx = tid + t * 256;
      int rr = idx >> 4, cc = idx & 15;
      As[rr][cc] = xi[(size_t)rowbase[rr] * DI + (k0 + cc)];
      int n = n0 + rr;
      Ws[rr][cc] = (n < N) ? wk[(size_t)n * K + (k0 + cc)] : 0.0f;
    }
    __syncthreads();
#pragma unroll
    for (int kk = 0; kk < 16; kk += 2) {
      float2 a[4], bb[4];
#pragma unroll
      for (int i = 0; i < 4; ++i) a[i] = *(const float2*)&As[ty + 16 * i][kk];
#pragma unroll
      for (int j = 0; j < 4; ++j) bb[j] = *(const float2*)&Ws[tx + 16 * j][kk];
#pragma unroll
      for (int i = 0; i < 4; ++i)
#pragma unroll
        for (int j = 0; j < 4; ++j)
          acc[i][j] += a[i].x * bb[j].x + a[i].y * bb[j].y;
    }
    __syncthreads();
  }
#pragma unroll
  for (int i = 0; i < 4; ++i) {
    int m = m0 + ty + 16 * i;
    int b = m >> 12, l = m & 4095;
#pragma unroll
    for (int j = 0; j < 4; ++j) {
      int n = n0 + tx + 16 * j;
      if (n >= N) continue;
      float v = acc[i][j];
      if (n < 12) {
        dt_buf[(((size_t)(b * 48 + kdir * 12 + n)) << 12) + l] =
            softplus_f(v + dt_bias[kdir * 12 + n]);
      } else if (n < 76) {
        size_t off = (((size_t)((b * 4 + kdir) << 12)) + l) * 64 + (n - 12);
        unsigned short hh = f2bf(v);
        Bhi[off] = hh;
        Blo[off] = f2bf(v - bf2f(hh));
      } else {
        size_t off = (((size_t)((b * 4 + kdir) << 12)) + l) * 64 + (n - 76);
        unsigned short hh = f2bf(v);
        Chi[off] = hh;
        Clo[off] = f2bf(v - bf2f(hh));
      }
    }
  }
}

// ---- D1 (MFMA): per (b,k,c): states_h[p,n] = sum_q (x[q,p]*dt_q*dls_q) * B[q,n]
__global__ __launch_bounds__(256) void k_states(const float* __restrict__ xi,
                                                const float* __restrict__ dt_buf,
                                                const unsigned short* __restrict__ Bhi,
                                                const unsigned short* __restrict__ Blo,
                                                const float* __restrict__ A_logs,
                                                float* __restrict__ states,
                                                float* __restrict__ cdec) {
  int c = blockIdx.x, k = blockIdx.y, b = blockIdx.z;
  __shared__ unsigned short Bt_h[4096], Bt_l[4096];  // [n][q] transposed, swizzled
  __shared__ unsigned short xw_h[2048], xw_l[2048];  // [p][q] swizzled
  int tid = threadIdx.x;
  int lane = tid & 63, w = tid >> 6;
  int cl = lane & 15, kb = lane >> 4;
  size_t Bbase = (((size_t)((b * 4 + k) << 12)) + c * 64) * 64;
  // transpose-stage B -> Bt[n][q]
  {
    int n = lane;
#pragma unroll
    for (int it = 0; it < 8; ++it) {
      int q0 = 2 * (w + it * 4);
      unsigned short h0 = Bhi[Bbase + (size_t)q0 * 64 + n];
      unsigned short h1 = Bhi[Bbase + (size_t)(q0 + 1) * 64 + n];
      unsigned short l0 = Blo[Bbase + (size_t)q0 * 64 + n];
      unsigned short l1 = Blo[Bbase + (size_t)(q0 + 1) * 64 + n];
      int e = swz(n, q0);
      *(unsigned int*)(Bt_h + e) = (unsigned)h0 | ((unsigned)h1 << 16);
      *(unsigned int*)(Bt_l + e) = (unsigned)l0 | ((unsigned)l1 << 16);
    }
  }
  int p_s = tid & 31, qg = tid >> 5;
  for (int r = 0; r < 12; ++r) {
    int h = k * 12 + r;
    float dtv = dt_buf[(((size_t)(b * 48 + h)) << 12) + c * 64 + lane];
    float v = dtv * (-__expf(A_logs[h]));
#pragma unroll
    for (int off = 1; off < 64; off <<= 1) {
      float u = __shfl_up(v, off, 64);
      if (lane >= off) v += u;
    }
    float alast = __shfl(v, 63, 64);
    float wq = dtv * __expf(alast - v);
    if (tid == 63) cdec[(b * 48 + h) * 64 + c] = __expf(alast);
    __syncthreads();  // prev head's MFMA reads done (r=0: covers Bt staging)
#pragma unroll
    for (int it = 0; it < 4; ++it) {
      int q0 = 2 * (qg + it * 8);
      int l0 = mapk(k, c * 64 + q0), l1 = mapk(k, c * 64 + q0 + 1);
      float w0 = __shfl(wq, q0, 64), w1 = __shfl(wq, q0 + 1, 64);
      float x0 = xi[((size_t)((b << 12) + l0)) * DI + r * 32 + p_s] * w0;
      float x1 = xi[((size_t)((b << 12) + l1)) * DI + r * 32 + p_s] * w1;
      unsigned short h0 = f2bf(x0), h1 = f2bf(x1);
      unsigned short L0 = f2bf(x0 - bf2f(h0)), L1 = f2bf(x1 - bf2f(h1));
      int e = swz(p_s, q0);
      *(unsigned int*)(xw_h + e) = (unsigned)h0 | ((unsigned)h1 << 16);
      *(unsigned int*)(xw_l + e) = (unsigned)L0 | ((unsigned)L1 << 16);
    }
    __syncthreads();
    f4v acc0 = {0.f, 0.f, 0.f, 0.f}, acc1 = {0.f, 0.f, 0.f, 0.f};
#pragma unroll
    for (int chunk = 0; chunk < 2; ++chunk) {
      int cb_ = chunk * 4 + kb;
      int nrow = w * 16 + cl;
      bf8v bh = *(const bf8v*)(Bt_h + foff(nrow, cb_));
      bf8v bl = *(const bf8v*)(Bt_l + foff(nrow, cb_));
      bf8v a0h = *(const bf8v*)(xw_h + foff(cl, cb_));
      bf8v a0l = *(const bf8v*)(xw_l + foff(cl, cb_));
      bf8v a1h = *(const bf8v*)(xw_h + foff(16 + cl, cb_));
      bf8v a1l = *(const bf8v*)(xw_l + foff(16 + cl, cb_));
      acc0 = mfma16(a0h, bh, acc0);
      acc0 = mfma16(a0h, bl, acc0);
      acc0 = mfma16(a0l, bh, acc0);
      acc1 = mfma16(a1h, bh, acc1);
      acc1 = mfma16(a1h, bl, acc1);
      acc1 = mfma16(a1l, bh, acc1);
    }
    size_t sbase = ((size_t)(b * 48 + h) * 64 + c) * 2048;
#pragma unroll
    for (int i = 0; i < 4; ++i) {
      int prow = kb * 4 + i;
      int n = w * 16 + cl;
      states[sbase + (size_t)prow * 64 + n] = acc0[i];
      states[sbase + (size_t)(16 + prow) * 64 + n] = acc1[i];
    }
  }
}

// ---- D2: inter-chunk scan, in place: states[c] <- prev_state (exclusive)
__global__ __launch_bounds__(256) void k_scan(float* __restrict__ states,
                                              const float* __restrict__ cdec) {
  int j = blockIdx.x;   // 0..7
  int bh = blockIdx.y;  // 0..95
  int tid = threadIdx.x;
  size_t base0 = (size_t)bh * 64 * 2048 + j * 256 + tid;
  float S = 0.0f;
  float nxt = states[base0];
  for (int c = 0; c < 64; ++c) {
    float cd = cdec[bh * 64 + c];
    size_t idx = base0 + (size_t)c * 2048;
    float tmp = nxt;
    if (c < 63) nxt = states[idx + 2048];
    states[idx] = S;
    S = cd * S + tmp;
  }
}

// ---- D3 (MFMA): per (b,k,c): CB^T once (regs); per head:
//      Y = G_h @ x  +  exp(Ac)*(C @ prev_h^T)  +  D*x
__global__ __launch_bounds__(256) void k_out(const float* __restrict__ xi,
                                             const float* __restrict__ dt_buf,
                                             const unsigned short* __restrict__ Bhi,
                                             const unsigned short* __restrict__ Blo,
                                             const unsigned short* __restrict__ Chi,
                                             const unsigned short* __restrict__ Clo,
                                             const float* __restrict__ A_logs,
                                             const float* __restrict__ Ds,
                                             const float* __restrict__ prevs,
                                             float* __restrict__ ys) {
  int c = blockIdx.x, k = blockIdx.y, b = blockIdx.z;
  __shared__ unsigned short C_h[4096], C_l[4096];  // [q][n] swizzled
  __shared__ unsigned short G_h[4096], G_l[4096];  // B during CB phase, then G [q][s]
  __shared__ unsigned short X_h[2048], X_l[2048];  // [p][s]
  __shared__ unsigned short P_h[2048], P_l[2048];  // [p][n]
  int tid = threadIdx.x;
  int lane = tid & 63, w = tid >> 6;
  int cl = lane & 15, kb = lane >> 4;
  size_t base64 = (((size_t)((b * 4 + k) << 12)) + c * 64) * 64;
  {
    int npair0 = tid & 31, n0 = npair0 * 2;
    int qq = tid >> 5;
#pragma unroll
    for (int it = 0; it < 8; ++it) {
      int q = qq + it * 8;
      size_t off = base64 + (size_t)q * 64 + n0;
      int e = swz(q, n0);
      *(unsigned int*)(C_h + e) = *(const unsigned int*)(Chi + off);
      *(unsigned int*)(C_l + e) = *(const unsigned int*)(Clo + off);
      *(unsigned int*)(G_h + e) = *(const unsigned int*)(Bhi + off);
      *(unsigned int*)(G_l + e) = *(const unsigned int*)(Blo + off);
    }
  }
  __syncthreads();
  // cache C A-fragments (rows q = w*16+cl) for CB^T and all heads' Y_off
  bf8v caf_h[2], caf_l[2];
#pragma unroll
  for (int chunk = 0; chunk < 2; ++chunk) {
    caf_h[chunk] = *(const bf8v*)(C_h + foff(w * 16 + cl, chunk * 4 + kb));
    caf_l[chunk] = *(const bf8v*)(C_l + foff(w * 16 + cl, chunk * 4 + kb));
  }
  // CB^T: cbt[St][i] = sum_n C[w*16+kb*4+i][n] * B[St*16+cl][n]
  f4v cbt[4];
#pragma unroll
  for (int St = 0; St < 4; ++St) cbt[St] = (f4v){0.f, 0.f, 0.f, 0.f};
#pragma unroll
  for (int St = 0; St < 4; ++St) {
    int srow = St * 16 + cl;
#pragma unroll
    for (int chunk = 0; chunk < 2; ++chunk) {
      bf8v bh = *(const bf8v*)(G_h + foff(srow, chunk * 4 + kb));
      bf8v bl = *(const bf8v*)(G_l + foff(srow, chunk * 4 + kb));
      cbt[St] = mfma16(caf_h[chunk], bh, cbt[St]);
      cbt[St] = mfma16(caf_h[chunk], bl, cbt[St]);
      cbt[St] = mfma16(caf_l[chunk], bh, cbt[St]);
    }
  }
  int p_s = tid & 31, sg = tid >> 5;
  for (int r = 0; r < 12; ++r) {
    int h = k * 12 + r;
    float dtv = dt_buf[(((size_t)(b * 48 + h)) << 12) + c * 64 + lane];
    float v = dtv * (-__expf(A_logs[h]));
#pragma unroll
    for (int off = 1; off < 64; off <<= 1) {
      float u = __shfl_up(v, off, 64);
      if (lane >= off) v += u;
    }
    float ea = __expf(v);
    __syncthreads();  // previous head's MFMA/epilogue reads done
    // stage X[p][s] = x[s][p]
#pragma unroll
    for (int it = 0; it < 4; ++it) {
      int s0 = 2 * (sg + it * 8);
      int l0 = mapk(k, c * 64 + s0), l1 = mapk(k, c * 64 + s0 + 1);
      float x0 = xi[((size_t)((b << 12) + l0)) * DI + r * 32 + p_s];
      float x1 = xi[((size_t)((b << 12) + l1)) * DI + r * 32 + p_s];
      unsigned short h0 = f2bf(x0), h1 = f2bf(x1);
      unsigned short L0 = f2bf(x0 - bf2f(h0)), L1 = f2bf(x1 - bf2f(h1));
      int e = swz(p_s, s0);
      *(unsigned int*)(X_h + e) = (unsigned)h0 | ((unsigned)h1 << 16);
      *(unsigned int*)(X_l + e) = (unsigned)L0 | ((unsigned)L1 << 16);
    }
    // stage P[p][n] = prev[p][n]
    size_t pbase = ((size_t)(b * 48 + h) * 64 + c) * 2048;
#pragma unroll
    for (int it = 0; it < 4; ++it) {
      int p = sg + it * 8;
      float2 f = *(const float2*)(prevs + pbase + (size_t)p * 64 + p_s * 2);
      unsigned short h0 = f2bf(f.x), h1 = f2bf(f.y);
      unsigned short L0 = f2bf(f.x - bf2f(h0)), L1 = f2bf(f.y - bf2f(h1));
      int e = swz(p, p_s * 2);
      *(unsigned int*)(P_h + e) = (unsigned)h0 | ((unsigned)h1 << 16);
      *(unsigned int*)(P_l + e) = (unsigned)L0 | ((unsigned)L1 << 16);
    }
    // build G[q][s] from register CB
    float vq[4];
#pragma unroll
    for (int i = 0; i < 4; ++i) vq[i] = __shfl(v, w * 16 + kb * 4 + i, 64);
#pragma unroll
    for (int St = 0; St < 4; ++St) {
      int s = St * 16 + cl;
      float vs = __shfl(v, s, 64);
      float dts = __shfl(dtv, s, 64);
#pragma unroll
      for (int i = 0; i < 4; ++i) {
        int q = w * 16 + kb * 4 + i;
        float g = (q >= s) ? cbt[St][i] * __expf(vq[i] - vs) * dts : 0.0f;
        unsigned short gh = f2bf(g);
        int e = swz(q, s);
        G_h[e] = gh;
        G_l[e] = f2bf(g - bf2f(gh));
      }
    }
    __syncthreads();  // staging + G ready
    f4v aD0 = {0.f, 0.f, 0.f, 0.f}, aD1 = aD0, aO0 = aD0, aO1 = aD0;
#pragma unroll
    for (int chunk = 0; chunk < 2; ++chunk) {
      int cb_ = chunk * 4 + kb;
      int qrow = w * 16 + cl;
      bf8v gh = *(const bf8v*)(G_h + foff(qrow, cb_));
      bf8v gl = *(const bf8v*)(G_l + foff(qrow, cb_));
      bf8v x0h = *(const bf8v*)(X_h + foff(cl, cb_));
      bf8v x0l = *(const bf8v*)(X_l + foff(cl, cb_));
      bf8v x1h = *(const bf8v*)(X_h + foff(16 + cl, cb_));
      bf8v x1l = *(const bf8v*)(X_l + foff(16 + cl, cb_));
      aD0 = mfma16(gh, x0h, aD0);
      aD0 = mfma16(gh, x0l, aD0);
      aD0 = mfma16(gl, x0h, aD0);
      aD1 = mfma16(gh, x1h, aD1);
      aD1 = mfma16(gh, x1l, aD1);
      aD1 = mfma16(gl, x1h, aD1);
      bf8v p0h = *(const bf8v*)(P_h + foff(cl, cb_));
      bf8v p0l = *(const bf8v*)(P_l + foff(cl, cb_));
      bf8v p1h = *(const bf8v*)(P_h + foff(16 + cl, cb_));
      bf8v p1l = *(const bf8v*)(P_l + foff(16 + cl, cb_));
      aO0 = mfma16(caf_h[chunk], p0h, aO0);
      aO0 = mfma16(caf_h[chunk], p0l, aO0);
      aO0 = mfma16(caf_l[chunk], p0h, aO0);
      aO1 = mfma16(caf_h[chunk], p1h, aO1);
      aO1 = mfma16(caf_h[chunk], p1l, aO1);
      aO1 = mfma16(caf_l[chunk], p1h, aO1);
    }
    float D0 = Ds[h * 32 + cl], D1 = Ds[h * 32 + 16 + cl];
    size_t ybase = ((size_t)((b * 4 + k) << 12) + c * 64) * DI + r * 32;
#pragma unroll
    for (int i = 0; i < 4; ++i) {
      int q = w * 16 + kb * 4 + i;
      float eaq = __shfl(ea, q, 64);
      int e0 = swz(cl, q), e1 = swz(16 + cl, q);
      float xv0 = bf2f(X_h[e0]) + bf2f(X_l[e0]);
      float xv1 = bf2f(X_h[e1]) + bf2f(X_l[e1]);
      ys[ybase + (size_t)q * DI + cl] = aD0[i] + eaq * aO0[i] + D0 * xv0;
      ys[ybase + (size_t)q * DI + 16 + cl] = aD1[i] + eaq * aO1[i] + D1 * xv1;
    }
  }
}

// ---- combine 4 directions + LayerNorm + gate
__global__ __launch_bounds__(128) void k_ln(const float* __restrict__ ys,
                                            const float* __restrict__ zg,
                                            const float* __restrict__ gg,
                                            const float* __restrict__ bb,
                                            float* __restrict__ y2) {
  int row = blockIdx.x;
  int b = row >> 12, l = row & 4095;
  int l1 = trf(l);
  int l2 = 4095 - l;
  int l3 = 4095 - l1;
  int tid = threadIdx.x;
  float v[3];
  size_t base = ((size_t)(b * 4)) << 12;
#pragma unroll
  for (int j = 0; j < 3; ++j) {
    int d = tid + j * 128;
    v[j] = ys[(base + l) * DI + d] + ys[(base + 4096 + l1) * DI + d] +
           ys[(base + 8192 + l2) * DI + d] + ys[(base + 12288 + l3) * DI + d];
  }
  __shared__ float red[2];
  float s = v[0] + v[1] + v[2];
#pragma unroll
  for (int off = 32; off > 0; off >>= 1) s += __shfl_down(s, off, 64);
  if ((tid & 63) == 0) red[tid >> 6] = s;
  __syncthreads();
  float mu = (red[0] + red[1]) * (1.0f / 384.0f);
  __syncthreads();
  float d2 = 0.0f;
#pragma unroll
  for (int j = 0; j < 3; ++j) {
    float dd = v[j] - mu;
    d2 += dd * dd;
  }
#pragma unroll
  for (int off = 32; off > 0; off >>= 1) d2 += __shfl_down(d2, off, 64);
  if ((tid & 63) == 0) red[tid >> 6] = d2;
  __syncthreads();
  float rstd = rsqrtf((red[0] + red[1]) * (1.0f / 384.0f) + 1e-5f);
#pragma unroll
  for (int j = 0; j < 3; ++j) {
    int d = tid + j * 128;
    float yv = (v[j] - mu) * rstd * gg[d] + bb[d];
    y2[(size_t)row * DI + d] = yv * zg[(size_t)row * DI + d];
  }
}

// ---- out_proj GEMM: y2[8192,384] @ w[192,384]^T -> out[8192,192]
__global__ __launch_bounds__(256) void k_outproj(const float* __restrict__ a,
                                                 const float* __restrict__ w,
                                                 float* __restrict__ out) {
  const int K = 384, NO = 192;
  __shared__ __align__(16) float As[64][18];
  __shared__ __align__(16) float Ws[64][18];
  int tid = threadIdx.x;
  int tx = tid & 15, ty = tid >> 4;
  int m0 = blockIdx.y * 64, n0 = blockIdx.x * 64;
  float acc[4][4] = {};
  for (int k0 = 0; k0 < K; k0 += 16) {
#pragma unroll
    for (int t = 0; t < 4; ++t) {
      int idx = tid + t * 256;
      int rr = idx >> 4, cc = idx & 15;
      As[rr][cc] = a[(size_t)(m0 + rr) * K + (k0 + cc)];
      Ws[rr][cc] = w[(size_t)(n0 + rr) * K + (k0 + cc)];
    }
    __syncthreads();
#pragma unroll
    for (int kk = 0; kk < 16; kk += 2) {
      float2 av[4], bv[4];
#pragma unroll
      for (int i = 0; i < 4; ++i) av[i] = *(const float2*)&As[ty + 16 * i][kk];
#pragma unroll
      for (int j = 0; j < 4; ++j) bv[j] = *(const float2*)&Ws[tx + 16 * j][kk];
#pragma unroll
      for (int i = 0; i < 4; ++i)
#pragma unroll
        for (int j = 0; j < 4; ++j)
          acc[i][j] += av[i].x * bv[j].x + av[i].y * bv[j].y;
    }
    __syncthreads();
  }
#pragma unroll
  for (int i = 0; i < 4; ++i) {
    int m = m0 + ty + 16 * i;
#pragma unroll
    for (int j = 0; j < 4; ++j) {
      int n = n0 + tx + 16 * j;
      out[(size_t)m * NO + n] = acc[i][j];
    }
  }
}

extern "C" void kernel_launch(void* const* d_in, const int* in_sizes, int n_in,
                              void* d_out, int out_size, void* d_ws, size_t ws_size,
                              hipStream_t stream) {
  const float* x = (const float*)d_in[0];
  const float* in_proj_w = (const float*)d_in[1];
  const float* conv_w = (const float*)d_in[2];
  const float* conv_b = (const float*)d_in[3];
  const float* x_proj_w = (const float*)d_in[4];
  const float* A_logs = (const float*)d_in[5];
  const float* Ds = (const float*)d_in[6];
  const float* dt_bias = (const float*)d_in[7];
  const float* out_norm_g = (const float*)d_in[8];
  const float* out_norm_b = (const float*)d_in[9];
  const float* out_proj_w = (const float*)d_in[10];
  float* out = (float*)d_out;

  float* ws = (float*)d_ws;
  float* xi_raw = ws;                        // 8192*384
  float* zg = xi_raw + 3145728;              // 8192*384
  float* xi = zg + 3145728;                  // 8192*384
  float* dt_buf = xi + 3145728;              // 2*48*4096
  unsigned short* Bhi = (unsigned short*)(dt_buf + 393216);  // 2*4*4096*64 u16
  unsigned short* Blo = Bhi + 2097152;
  unsigned short* Chi = Blo + 2097152;
  unsigned short* Clo = Chi + 2097152;
  float* states = (float*)(Clo + 2097152);   // 2*48*64*2048
  float* cdec = states + 12582912;           // 2*48*64
  float* ys = cdec + 6144;                   // 2*4*4096*384
  float* y2 = xi_raw;                        // alias (xi_raw dead after conv)

  k_inproj<<<dim3(12, 128), 256, 0, stream>>>(x, in_proj_w, xi_raw, zg);
  k_conv<<<dim3(12288), 256, 0, stream>>>(xi_raw, conv_w, conv_b, xi);
  k_xproj<<<dim3(3, 128, 4), 256, 0, stream>>>(xi, x_proj_w, dt_bias, dt_buf, Bhi, Blo, Chi, Clo);
  k_states<<<dim3(64, 4, 2), 256, 0, stream>>>(xi, dt_buf, Bhi, Blo, A_logs, states, cdec);
  k_scan<<<dim3(8, 96), 256, 0, stream>>>(states, cdec);
  k_out<<<dim3(64, 4, 2), 256, 0, stream>>>(xi, dt_buf, Bhi, Blo, Chi, Clo, A_logs, Ds, states, ys);
  k_ln<<<dim3(8192), 128, 0, stream>>>(ys, zg, out_norm_g, out_norm_b, y2);
  k_outproj<<<dim3(3, 128), 256, 0, stream>>>(y2, out_proj_w, out);
}

// Round 4
// 224.899 us; speedup vs baseline: 4.6197x; 1.9564x over previous
//
#include <hip/hip_runtime.h>
#include <math.h>

#define DI 384   // d_inner

typedef __attribute__((ext_vector_type(8))) short bf8v;   // 8 bf16
typedef __attribute__((ext_vector_type(4))) float f4v;    // 4 fp32

__device__ __forceinline__ f4v mfma16(bf8v a, bf8v b, f4v c) {
  return __builtin_amdgcn_mfma_f32_16x16x32_bf16(a, b, c, 0, 0, 0);
}

__device__ __forceinline__ int trf(int l) { return ((l & 63) << 6) | (l >> 6); }
__device__ __forceinline__ int mapk(int k, int l) {
  if (k == 0) return l;
  if (k == 1) return trf(l);
  if (k == 2) return 4095 - l;
  return trf(4095 - l);
}
__device__ __forceinline__ float gelu_f(float x) {
  return 0.5f * x * (1.0f + erff(x * 0.7071067811865475f));
}
__device__ __forceinline__ float softplus_f(float x) {
  return (x > 20.0f) ? x : log1pf(expf(x));
}
__device__ __forceinline__ unsigned short f2bf(float f) {
  unsigned u = __float_as_uint(f);
  unsigned r = (u + 0x7fff + ((u >> 16) & 1)) >> 16;
  return (unsigned short)r;
}
__device__ __forceinline__ float bf2f(unsigned short h) {
  return __uint_as_float(((unsigned)h) << 16);
}
// element offset in a [R][64] u16 plane, XOR-swizzled per 8-elem block
__device__ __forceinline__ int swz(int row, int col) {
  return (row << 6) + ((((col >> 3) ^ (row & 7)) << 3) | (col & 7));
}
__device__ __forceinline__ int foff(int row, int cb) {
  return (row << 6) + ((cb ^ (row & 7)) << 3);
}

// ---- fp32 -> bf16 hi/lo planes
__global__ __launch_bounds__(256) void k_cvt(const float* __restrict__ src,
                                             unsigned short* __restrict__ hi,
                                             unsigned short* __restrict__ lo, int n) {
  int i = blockIdx.x * 256 + threadIdx.x;
  if (i >= n) return;
  float v = src[i];
  unsigned short h = f2bf(v);
  hi[i] = h;
  lo[i] = f2bf(v - bf2f(h));
}

// ---- in_proj (MFMA): x[8192,192] @ w[768,192]^T -> xi_raw fp32, zg fp32
__global__ __launch_bounds__(256) void k_inproj(const unsigned short* __restrict__ Ahi,
                                                const unsigned short* __restrict__ Alo,
                                                const unsigned short* __restrict__ Whi,
                                                const unsigned short* __restrict__ Wlo,
                                                float* __restrict__ xi_raw,
                                                float* __restrict__ zg) {
  const int K = 192;
  __shared__ unsigned short Ah[4096], Al[4096], Bh[4096], Bl[4096];
  int tid = threadIdx.x;
  int lane = tid & 63, w = tid >> 6;
  int cl = lane & 15, kb = lane >> 4;
  int wm = w >> 1, wn = w & 1;
  int m0 = blockIdx.y * 64, n0 = blockIdx.x * 64;
  f4v acc[2][2];
  acc[0][0] = acc[0][1] = acc[1][0] = acc[1][1] = (f4v){0.f, 0.f, 0.f, 0.f};
  for (int k0 = 0; k0 < K; k0 += 64) {
#pragma unroll
    for (int u = 0; u < 2; ++u) {
      int unit = tid + u * 256;
      int row = unit >> 3, blk = unit & 7;
      int e = foff(row, blk);
      size_t ga = (size_t)(m0 + row) * K + k0 + blk * 8;
      size_t gb = (size_t)(n0 + row) * K + k0 + blk * 8;
      *(bf8v*)(Ah + e) = *(const bf8v*)(Ahi + ga);
      *(bf8v*)(Al + e) = *(const bf8v*)(Alo + ga);
      *(bf8v*)(Bh + e) = *(const bf8v*)(Whi + gb);
      *(bf8v*)(Bl + e) = *(const bf8v*)(Wlo + gb);
    }
    __syncthreads();
#pragma unroll
    for (int chunk = 0; chunk < 2; ++chunk) {
      int cb = chunk * 4 + kb;
      bf8v ah[2], al[2], bh[2], bl[2];
#pragma unroll
      for (int mi = 0; mi < 2; ++mi) {
        ah[mi] = *(const bf8v*)(Ah + foff(wm * 32 + mi * 16 + cl, cb));
        al[mi] = *(const bf8v*)(Al + foff(wm * 32 + mi * 16 + cl, cb));
      }
#pragma unroll
      for (int ni = 0; ni < 2; ++ni) {
        bh[ni] = *(const bf8v*)(Bh + foff(wn * 32 + ni * 16 + cl, cb));
        bl[ni] = *(const bf8v*)(Bl + foff(wn * 32 + ni * 16 + cl, cb));
      }
#pragma unroll
      for (int mi = 0; mi < 2; ++mi)
#pragma unroll
        for (int ni = 0; ni < 2; ++ni) {
          acc[mi][ni] = mfma16(ah[mi], bh[ni], acc[mi][ni]);
          acc[mi][ni] = mfma16(ah[mi], bl[ni], acc[mi][ni]);
          acc[mi][ni] = mfma16(al[mi], bh[ni], acc[mi][ni]);
        }
    }
    __syncthreads();
  }
#pragma unroll
  for (int mi = 0; mi < 2; ++mi)
#pragma unroll
    for (int ni = 0; ni < 2; ++ni)
#pragma unroll
      for (int i = 0; i < 4; ++i) {
        int m = m0 + wm * 32 + mi * 16 + kb * 4 + i;
        int n = n0 + wn * 32 + ni * 16 + cl;
        float v = acc[mi][ni][i];
        if (n < DI) xi_raw[(size_t)m * DI + n] = v;
        else zg[(size_t)m * DI + (n - DI)] = gelu_f(v);
      }
}

// ---- depthwise 3x3 conv + bias + gelu -> xi hi/lo planes
__global__ __launch_bounds__(256) void k_conv(const float* __restrict__ xin,
                                              const float* __restrict__ cw,
                                              const float* __restrict__ cb,
                                              unsigned short* __restrict__ xhi,
                                              unsigned short* __restrict__ xlo) {
  int idx = blockIdx.x * 256 + threadIdx.x;  // over 2*4096*384
  int c = idx % DI;
  int lf = idx / DI;
  int b = lf >> 12;
  int l = lf & 4095;
  int h = l >> 6, w = l & 63;
  float acc = cb[c];
#pragma unroll
  for (int dh = -1; dh <= 1; ++dh) {
    int hh = h + dh;
    if ((unsigned)hh >= 64u) continue;
#pragma unroll
    for (int dw = -1; dw <= 1; ++dw) {
      int ww = w + dw;
      if ((unsigned)ww >= 64u) continue;
      acc += xin[((size_t)((b << 12) | (hh << 6) | ww)) * DI + c] *
             cw[c * 9 + (dh + 1) * 3 + (dw + 1)];
    }
  }
  float g = gelu_f(acc);
  unsigned short hv = f2bf(g);
  xhi[(size_t)idx] = hv;
  xlo[(size_t)idx] = f2bf(g - bf2f(hv));
}

// ---- x_proj (MFMA, gathered rows): xs[.,384] @ wk[140,384]^T per direction
__global__ __launch_bounds__(256) void k_xproj(const unsigned short* __restrict__ xhi,
                                               const unsigned short* __restrict__ xlo,
                                               const unsigned short* __restrict__ Whi,
                                               const unsigned short* __restrict__ Wlo,
                                               const float* __restrict__ dt_bias,
                                               float* __restrict__ dt_buf,
                                               unsigned short* __restrict__ Bhi,
                                               unsigned short* __restrict__ Blo,
                                               unsigned short* __restrict__ Chi,
                                               unsigned short* __restrict__ Clo) {
  const int K = DI, N = 140;
  int kdir = blockIdx.z;
  __shared__ unsigned short Ah[4096], Al[4096], Bh[4096], Bl[4096];
  __shared__ int rowbase[64];
  int tid = threadIdx.x;
  int lane = tid & 63, w = tid >> 6;
  int cl = lane & 15, kb = lane >> 4;
  int wm = w >> 1, wn = w & 1;
  int m0 = blockIdx.y * 64, n0 = blockIdx.x * 64;
  if (tid < 64) {
    int m = m0 + tid;
    int b = m >> 12, l = m & 4095;
    rowbase[tid] = (b << 12) + mapk(kdir, l);
  }
  const unsigned short* wkh = Whi + (size_t)kdir * N * K;
  const unsigned short* wkl = Wlo + (size_t)kdir * N * K;
  f4v acc[2][2];
  acc[0][0] = acc[0][1] = acc[1][0] = acc[1][1] = (f4v){0.f, 0.f, 0.f, 0.f};
  __syncthreads();
  for (int k0 = 0; k0 < K; k0 += 64) {
#pragma unroll
    for (int u = 0; u < 2; ++u) {
      int unit = tid + u * 256;
      int row = unit >> 3, blk = unit & 7;
      int e = foff(row, blk);
      size_t ga = (size_t)rowbase[row] * K + k0 + blk * 8;
      *(bf8v*)(Ah + e) = *(const bf8v*)(xhi + ga);
      *(bf8v*)(Al + e) = *(const bf8v*)(xlo + ga);
      int n = n0 + row;
      if (n < N) {
        size_t gb = (size_t)n * K + k0 + blk * 8;
        *(bf8v*)(Bh + e) = *(const bf8v*)(wkh + gb);
        *(bf8v*)(Bl + e) = *(const bf8v*)(wkl + gb);
      } else {
        bf8v z = {0, 0, 0, 0, 0, 0, 0, 0};
        *(bf8v*)(Bh + e) = z;
        *(bf8v*)(Bl + e) = z;
      }
    }
    __syncthreads();
#pragma unroll
    for (int chunk = 0; chunk < 2; ++chunk) {
      int cb = chunk * 4 + kb;
      bf8v ah[2], al[2], bh[2], bl[2];
#pragma unroll
      for (int mi = 0; mi < 2; ++mi) {
        ah[mi] = *(const bf8v*)(Ah + foff(wm * 32 + mi * 16 + cl, cb));
        al[mi] = *(const bf8v*)(Al + foff(wm * 32 + mi * 16 + cl, cb));
      }
#pragma unroll
      for (int ni = 0; ni < 2; ++ni) {
        bh[ni] = *(const bf8v*)(Bh + foff(wn * 32 + ni * 16 + cl, cb));
        bl[ni] = *(const bf8v*)(Bl + foff(wn * 32 + ni * 16 + cl, cb));
      }
#pragma unroll
      for (int mi = 0; mi < 2; ++mi)
#pragma unroll
        for (int ni = 0; ni < 2; ++ni) {
          acc[mi][ni] = mfma16(ah[mi], bh[ni], acc[mi][ni]);
          acc[mi][ni] = mfma16(ah[mi], bl[ni], acc[mi][ni]);
          acc[mi][ni] = mfma16(al[mi], bh[ni], acc[mi][ni]);
        }
    }
    __syncthreads();
  }
#pragma unroll
  for (int mi = 0; mi < 2; ++mi)
#pragma unroll
    for (int ni = 0; ni < 2; ++ni)
#pragma unroll
      for (int i = 0; i < 4; ++i) {
        int m = m0 + wm * 32 + mi * 16 + kb * 4 + i;
        int n = n0 + wn * 32 + ni * 16 + cl;
        if (n >= N) continue;
        float v = acc[mi][ni][i];
        int b = m >> 12, l = m & 4095;
        if (n < 12) {
          dt_buf[(((size_t)(b * 48 + kdir * 12 + n)) << 12) + l] =
              softplus_f(v + dt_bias[kdir * 12 + n]);
        } else if (n < 76) {
          size_t off = (((size_t)((b * 4 + kdir) << 12)) + l) * 64 + (n - 12);
          unsigned short hh = f2bf(v);
          Bhi[off] = hh;
          Blo[off] = f2bf(v - bf2f(hh));
        } else {
          size_t off = (((size_t)((b * 4 + kdir) << 12)) + l) * 64 + (n - 76);
          unsigned short hh = f2bf(v);
          Chi[off] = hh;
          Clo[off] = f2bf(v - bf2f(hh));
        }
      }
}

// ---- D1 (MFMA): per (b,k,c): states_h[p,n] = sum_q (x[q,p]*dt_q*dls_q) * B[q,n]
__global__ __launch_bounds__(256) void k_states(const unsigned short* __restrict__ xhi,
                                                const unsigned short* __restrict__ xlo,
                                                const float* __restrict__ dt_buf,
                                                const unsigned short* __restrict__ Bhi,
                                                const unsigned short* __restrict__ Blo,
                                                const float* __restrict__ A_logs,
                                                float* __restrict__ states,
                                                float* __restrict__ cdec) {
  int c = blockIdx.x, k = blockIdx.y, b = blockIdx.z;
  __shared__ unsigned short Bt_h[4096], Bt_l[4096];  // [n][q] transposed, swizzled
  __shared__ unsigned short xw_h[2048], xw_l[2048];  // [p][q] swizzled
  int tid = threadIdx.x;
  int lane = tid & 63, w = tid >> 6;
  int cl = lane & 15, kb = lane >> 4;
  size_t Bbase = (((size_t)((b * 4 + k) << 12)) + c * 64) * 64;
  // transpose-stage B -> Bt[n][q]
  {
    int n = lane;
#pragma unroll
    for (int it = 0; it < 8; ++it) {
      int q0 = 2 * (w + it * 4);
      unsigned short h0 = Bhi[Bbase + (size_t)q0 * 64 + n];
      unsigned short h1 = Bhi[Bbase + (size_t)(q0 + 1) * 64 + n];
      unsigned short l0 = Blo[Bbase + (size_t)q0 * 64 + n];
      unsigned short l1 = Blo[Bbase + (size_t)(q0 + 1) * 64 + n];
      int e = swz(n, q0);
      *(unsigned int*)(Bt_h + e) = (unsigned)h0 | ((unsigned)h1 << 16);
      *(unsigned int*)(Bt_l + e) = (unsigned)l0 | ((unsigned)l1 << 16);
    }
  }
  int p_s = tid & 31, qg = tid >> 5;
  for (int r = 0; r < 12; ++r) {
    int h = k * 12 + r;
    float dtv = dt_buf[(((size_t)(b * 48 + h)) << 12) + c * 64 + lane];
    float v = dtv * (-__expf(A_logs[h]));
#pragma unroll
    for (int off = 1; off < 64; off <<= 1) {
      float u = __shfl_up(v, off, 64);
      if (lane >= off) v += u;
    }
    float alast = __shfl(v, 63, 64);
    float wq = dtv * __expf(alast - v);
    if (tid == 63) cdec[(b * 48 + h) * 64 + c] = __expf(alast);
    __syncthreads();  // prev head's MFMA reads done (r=0: covers Bt staging)
#pragma unroll
    for (int it = 0; it < 4; ++it) {
      int q0 = 2 * (qg + it * 8);
      int l0 = mapk(k, c * 64 + q0), l1 = mapk(k, c * 64 + q0 + 1);
      float w0 = __shfl(wq, q0, 64), w1 = __shfl(wq, q0 + 1, 64);
      size_t o0 = ((size_t)((b << 12) + l0)) * DI + r * 32 + p_s;
      size_t o1 = ((size_t)((b << 12) + l1)) * DI + r * 32 + p_s;
      float x0 = (bf2f(xhi[o0]) + bf2f(xlo[o0])) * w0;
      float x1 = (bf2f(xhi[o1]) + bf2f(xlo[o1])) * w1;
      unsigned short h0 = f2bf(x0), h1 = f2bf(x1);
      unsigned short L0 = f2bf(x0 - bf2f(h0)), L1 = f2bf(x1 - bf2f(h1));
      int e = swz(p_s, q0);
      *(unsigned int*)(xw_h + e) = (unsigned)h0 | ((unsigned)h1 << 16);
      *(unsigned int*)(xw_l + e) = (unsigned)L0 | ((unsigned)L1 << 16);
    }
    __syncthreads();
    f4v acc0 = {0.f, 0.f, 0.f, 0.f}, acc1 = {0.f, 0.f, 0.f, 0.f};
#pragma unroll
    for (int chunk = 0; chunk < 2; ++chunk) {
      int cb_ = chunk * 4 + kb;
      int nrow = w * 16 + cl;
      bf8v bh = *(const bf8v*)(Bt_h + foff(nrow, cb_));
      bf8v bl = *(const bf8v*)(Bt_l + foff(nrow, cb_));
      bf8v a0h = *(const bf8v*)(xw_h + foff(cl, cb_));
      bf8v a0l = *(const bf8v*)(xw_l + foff(cl, cb_));
      bf8v a1h = *(const bf8v*)(xw_h + foff(16 + cl, cb_));
      bf8v a1l = *(const bf8v*)(xw_l + foff(16 + cl, cb_));
      acc0 = mfma16(a0h, bh, acc0);
      acc0 = mfma16(a0h, bl, acc0);
      acc0 = mfma16(a0l, bh, acc0);
      acc1 = mfma16(a1h, bh, acc1);
      acc1 = mfma16(a1h, bl, acc1);
      acc1 = mfma16(a1l, bh, acc1);
    }
    size_t sbase = ((size_t)(b * 48 + h) * 64 + c) * 2048;
#pragma unroll
    for (int i = 0; i < 4; ++i) {
      int prow = kb * 4 + i;
      int n = w * 16 + cl;
      states[sbase + (size_t)prow * 64 + n] = acc0[i];
      states[sbase + (size_t)(16 + prow) * 64 + n] = acc1[i];
    }
  }
}

// ---- D2: inter-chunk scan, in place: states[c] <- prev_state (exclusive)
__global__ __launch_bounds__(256) void k_scan(float* __restrict__ states,
                                              const float* __restrict__ cdec) {
  int j = blockIdx.x;   // 0..7
  int bh = blockIdx.y;  // 0..95
  int tid = threadIdx.x;
  size_t base0 = (size_t)bh * 64 * 2048 + j * 256 + tid;
  float S = 0.0f;
  float nxt = states[base0];
  for (int c = 0; c < 64; ++c) {
    float cd = cdec[bh * 64 + c];
    size_t idx = base0 + (size_t)c * 2048;
    float tmp = nxt;
    if (c < 63) nxt = states[idx + 2048];
    states[idx] = S;
    S = cd * S + tmp;
  }
}

// ---- D3 (MFMA): per (b,k,c): CB^T once (regs); per head:
//      Y = G_h @ x  +  exp(Ac)*(C @ prev_h^T)  +  D*x
__global__ __launch_bounds__(256) void k_out(const unsigned short* __restrict__ xhi,
                                             const unsigned short* __restrict__ xlo,
                                             const float* __restrict__ dt_buf,
                                             const unsigned short* __restrict__ Bhi,
                                             const unsigned short* __restrict__ Blo,
                                             const unsigned short* __restrict__ Chi,
                                             const unsigned short* __restrict__ Clo,
                                             const float* __restrict__ A_logs,
                                             const float* __restrict__ Ds,
                                             const float* __restrict__ prevs,
                                             float* __restrict__ ys) {
  int c = blockIdx.x, k = blockIdx.y, b = blockIdx.z;
  __shared__ unsigned short C_h[4096], C_l[4096];  // [q][n] swizzled
  __shared__ unsigned short G_h[4096], G_l[4096];  // B during CB phase, then G [q][s]
  __shared__ unsigned short X_h[2048], X_l[2048];  // [p][s]
  __shared__ unsigned short P_h[2048], P_l[2048];  // [p][n]
  int tid = threadIdx.x;
  int lane = tid & 63, w = tid >> 6;
  int cl = lane & 15, kb = lane >> 4;
  size_t base64 = (((size_t)((b * 4 + k) << 12)) + c * 64) * 64;
  {
    int npair0 = tid & 31, n0 = npair0 * 2;
    int qq = tid >> 5;
#pragma unroll
    for (int it = 0; it < 8; ++it) {
      int q = qq + it * 8;
      size_t off = base64 + (size_t)q * 64 + n0;
      int e = swz(q, n0);
      *(unsigned int*)(C_h + e) = *(const unsigned int*)(Chi + off);
      *(unsigned int*)(C_l + e) = *(const unsigned int*)(Clo + off);
      *(unsigned int*)(G_h + e) = *(const unsigned int*)(Bhi + off);
      *(unsigned int*)(G_l + e) = *(const unsigned int*)(Blo + off);
    }
  }
  __syncthreads();
  // cache C A-fragments (rows q = w*16+cl) for CB^T and all heads' Y_off
  bf8v caf_h[2], caf_l[2];
#pragma unroll
  for (int chunk = 0; chunk < 2; ++chunk) {
    caf_h[chunk] = *(const bf8v*)(C_h + foff(w * 16 + cl, chunk * 4 + kb));
    caf_l[chunk] = *(const bf8v*)(C_l + foff(w * 16 + cl, chunk * 4 + kb));
  }
  // CB^T: cbt[St][i] = sum_n C[w*16+kb*4+i][n] * B[St*16+cl][n]
  f4v cbt[4];
#pragma unroll
  for (int St = 0; St < 4; ++St) cbt[St] = (f4v){0.f, 0.f, 0.f, 0.f};
#pragma unroll
  for (int St = 0; St < 4; ++St) {
    int srow = St * 16 + cl;
#pragma unroll
    for (int chunk = 0; chunk < 2; ++chunk) {
      bf8v bh = *(const bf8v*)(G_h + foff(srow, chunk * 4 + kb));
      bf8v bl = *(const bf8v*)(G_l + foff(srow, chunk * 4 + kb));
      cbt[St] = mfma16(caf_h[chunk], bh, cbt[St]);
      cbt[St] = mfma16(caf_h[chunk], bl, cbt[St]);
      cbt[St] = mfma16(caf_l[chunk], bh, cbt[St]);
    }
  }
  int p_s = tid & 31, sg = tid >> 5;
  for (int r = 0; r < 12; ++r) {
    int h = k * 12 + r;
    float dtv = dt_buf[(((size_t)(b * 48 + h)) << 12) + c * 64 + lane];
    float v = dtv * (-__expf(A_logs[h]));
#pragma unroll
    for (int off = 1; off < 64; off <<= 1) {
      float u = __shfl_up(v, off, 64);
      if (lane >= off) v += u;
    }
    float ea = __expf(v);
    __syncthreads();  // previous head's MFMA/epilogue reads done
    // stage X[p][s] = x[s][p] from hi/lo planes (no split math needed)
#pragma unroll
    for (int it = 0; it < 4; ++it) {
      int s0 = 2 * (sg + it * 8);
      int l0 = mapk(k, c * 64 + s0), l1 = mapk(k, c * 64 + s0 + 1);
      size_t o0 = ((size_t)((b << 12) + l0)) * DI + r * 32 + p_s;
      size_t o1 = ((size_t)((b << 12) + l1)) * DI + r * 32 + p_s;
      int e = swz(p_s, s0);
      *(unsigned int*)(X_h + e) = (unsigned)xhi[o0] | ((unsigned)xhi[o1] << 16);
      *(unsigned int*)(X_l + e) = (unsigned)xlo[o0] | ((unsigned)xlo[o1] << 16);
    }
    // stage P[p][n] = prev[p][n]
    size_t pbase = ((size_t)(b * 48 + h) * 64 + c) * 2048;
#pragma unroll
    for (int it = 0; it < 4; ++it) {
      int p = sg + it * 8;
      float2 f = *(const float2*)(prevs + pbase + (size_t)p * 64 + p_s * 2);
      unsigned short h0 = f2bf(f.x), h1 = f2bf(f.y);
      unsigned short L0 = f2bf(f.x - bf2f(h0)), L1 = f2bf(f.y - bf2f(h1));
      int e = swz(p, p_s * 2);
      *(unsigned int*)(P_h + e) = (unsigned)h0 | ((unsigned)h1 << 16);
      *(unsigned int*)(P_l + e) = (unsigned)L0 | ((unsigned)L1 << 16);
    }
    // build G[q][s] from register CB
    float vq[4];
#pragma unroll
    for (int i = 0; i < 4; ++i) vq[i] = __shfl(v, w * 16 + kb * 4 + i, 64);
#pragma unroll
    for (int St = 0; St < 4; ++St) {
      int s = St * 16 + cl;
      float vs = __shfl(v, s, 64);
      float dts = __shfl(dtv, s, 64);
#pragma unroll
      for (int i = 0; i < 4; ++i) {
        int q = w * 16 + kb * 4 + i;
        float g = (q >= s) ? cbt[St][i] * __expf(vq[i] - vs) * dts : 0.0f;
        unsigned short gh = f2bf(g);
        int e = swz(q, s);
        G_h[e] = gh;
        G_l[e] = f2bf(g - bf2f(gh));
      }
    }
    __syncthreads();  // staging + G ready
    f4v aD0 = {0.f, 0.f, 0.f, 0.f}, aD1 = aD0, aO0 = aD0, aO1 = aD0;
#pragma unroll
    for (int chunk = 0; chunk < 2; ++chunk) {
      int cb_ = chunk * 4 + kb;
      int qrow = w * 16 + cl;
      bf8v gh = *(const bf8v*)(G_h + foff(qrow, cb_));
      bf8v gl = *(const bf8v*)(G_l + foff(qrow, cb_));
      bf8v x0h = *(const bf8v*)(X_h + foff(cl, cb_));
      bf8v x0l = *(const bf8v*)(X_l + foff(cl, cb_));
      bf8v x1h = *(const bf8v*)(X_h + foff(16 + cl, cb_));
      bf8v x1l = *(const bf8v*)(X_l + foff(16 + cl, cb_));
      aD0 = mfma16(gh, x0h, aD0);
      aD0 = mfma16(gh, x0l, aD0);
      aD0 = mfma16(gl, x0h, aD0);
      aD1 = mfma16(gh, x1h, aD1);
      aD1 = mfma16(gh, x1l, aD1);
      aD1 = mfma16(gl, x1h, aD1);
      bf8v p0h = *(const bf8v*)(P_h + foff(cl, cb_));
      bf8v p0l = *(const bf8v*)(P_l + foff(cl, cb_));
      bf8v p1h = *(const bf8v*)(P_h + foff(16 + cl, cb_));
      bf8v p1l = *(const bf8v*)(P_l + foff(16 + cl, cb_));
      aO0 = mfma16(caf_h[chunk], p0h, aO0);
      aO0 = mfma16(caf_h[chunk], p0l, aO0);
      aO0 = mfma16(caf_l[chunk], p0h, aO0);
      aO1 = mfma16(caf_h[chunk], p1h, aO1);
      aO1 = mfma16(caf_h[chunk], p1l, aO1);
      aO1 = mfma16(caf_l[chunk], p1h, aO1);
    }
    float D0 = Ds[h * 32 + cl], D1 = Ds[h * 32 + 16 + cl];
    size_t ybase = ((size_t)((b * 4 + k) << 12) + c * 64) * DI + r * 32;
#pragma unroll
    for (int i = 0; i < 4; ++i) {
      int q = w * 16 + kb * 4 + i;
      float eaq = __shfl(ea, q, 64);
      int e0 = swz(cl, q), e1 = swz(16 + cl, q);
      float xv0 = bf2f(X_h[e0]) + bf2f(X_l[e0]);
      float xv1 = bf2f(X_h[e1]) + bf2f(X_l[e1]);
      ys[ybase + (size_t)q * DI + cl] = aD0[i] + eaq * aO0[i] + D0 * xv0;
      ys[ybase + (size_t)q * DI + 16 + cl] = aD1[i] + eaq * aO1[i] + D1 * xv1;
    }
  }
}

// ---- combine 4 directions + LayerNorm + gate -> y2 hi/lo planes
__global__ __launch_bounds__(128) void k_ln(const float* __restrict__ ys,
                                            const float* __restrict__ zg,
                                            const float* __restrict__ gg,
                                            const float* __restrict__ bb,
                                            unsigned short* __restrict__ y2h,
                                            unsigned short* __restrict__ y2l) {
  int row = blockIdx.x;
  int b = row >> 12, l = row & 4095;
  int l1 = trf(l);
  int l2 = 4095 - l;
  int l3 = 4095 - l1;
  int tid = threadIdx.x;
  float v[3];
  size_t base = ((size_t)(b * 4)) << 12;
#pragma unroll
  for (int j = 0; j < 3; ++j) {
    int d = tid + j * 128;
    v[j] = ys[(base + l) * DI + d] + ys[(base + 4096 + l1) * DI + d] +
           ys[(base + 8192 + l2) * DI + d] + ys[(base + 12288 + l3) * DI + d];
  }
  __shared__ float red[2];
  float s = v[0] + v[1] + v[2];
#pragma unroll
  for (int off = 32; off > 0; off >>= 1) s += __shfl_down(s, off, 64);
  if ((tid & 63) == 0) red[tid >> 6] = s;
  __syncthreads();
  float mu = (red[0] + red[1]) * (1.0f / 384.0f);
  __syncthreads();
  float d2 = 0.0f;
#pragma unroll
  for (int j = 0; j < 3; ++j) {
    float dd = v[j] - mu;
    d2 += dd * dd;
  }
#pragma unroll
  for (int off = 32; off > 0; off >>= 1) d2 += __shfl_down(d2, off, 64);
  if ((tid & 63) == 0) red[tid >> 6] = d2;
  __syncthreads();
  float rstd = rsqrtf((red[0] + red[1]) * (1.0f / 384.0f) + 1e-5f);
#pragma unroll
  for (int j = 0; j < 3; ++j) {
    int d = tid + j * 128;
    float yv = (v[j] - mu) * rstd * gg[d] + bb[d];
    float o = yv * zg[(size_t)row * DI + d];
    unsigned short hh = f2bf(o);
    y2h[(size_t)row * DI + d] = hh;
    y2l[(size_t)row * DI + d] = f2bf(o - bf2f(hh));
  }
}

// ---- out_proj (MFMA): y2[8192,384] @ w[192,384]^T -> out fp32 [8192,192]
__global__ __launch_bounds__(256) void k_outproj(const unsigned short* __restrict__ Ahi,
                                                 const unsigned short* __restrict__ Alo,
                                                 const unsigned short* __restrict__ Whi,
                                                 const unsigned short* __restrict__ Wlo,
                                                 float* __restrict__ out) {
  const int K = DI, NO = 192;
  __shared__ unsigned short Ah[4096], Al[4096], Bh[4096], Bl[4096];
  int tid = threadIdx.x;
  int lane = tid & 63, w = tid >> 6;
  int cl = lane & 15, kb = lane >> 4;
  int wm = w >> 1, wn = w & 1;
  int m0 = blockIdx.y * 64, n0 = blockIdx.x * 64;
  f4v acc[2][2];
  acc[0][0] = acc[0][1] = acc[1][0] = acc[1][1] = (f4v){0.f, 0.f, 0.f, 0.f};
  for (int k0 = 0; k0 < K; k0 += 64) {
#pragma unroll
    for (int u = 0; u < 2; ++u) {
      int unit = tid + u * 256;
      int row = unit >> 3, blk = unit & 7;
      int e = foff(row, blk);
      size_t ga = (size_t)(m0 + row) * K + k0 + blk * 8;
      size_t gb = (size_t)(n0 + row) * K + k0 + blk * 8;
      *(bf8v*)(Ah + e) = *(const bf8v*)(Ahi + ga);
      *(bf8v*)(Al + e) = *(const bf8v*)(Alo + ga);
      *(bf8v*)(Bh + e) = *(const bf8v*)(Whi + gb);
      *(bf8v*)(Bl + e) = *(const bf8v*)(Wlo + gb);
    }
    __syncthreads();
#pragma unroll
    for (int chunk = 0; chunk < 2; ++chunk) {
      int cb = chunk * 4 + kb;
      bf8v ah[2], al[2], bh[2], bl[2];
#pragma unroll
      for (int mi = 0; mi < 2; ++mi) {
        ah[mi] = *(const bf8v*)(Ah + foff(wm * 32 + mi * 16 + cl, cb));
        al[mi] = *(const bf8v*)(Al + foff(wm * 32 + mi * 16 + cl, cb));
      }
#pragma unroll
      for (int ni = 0; ni < 2; ++ni) {
        bh[ni] = *(const bf8v*)(Bh + foff(wn * 32 + ni * 16 + cl, cb));
        bl[ni] = *(const bf8v*)(Bl + foff(wn * 32 + ni * 16 + cl, cb));
      }
#pragma unroll
      for (int mi = 0; mi < 2; ++mi)
#pragma unroll
        for (int ni = 0; ni < 2; ++ni) {
          acc[mi][ni] = mfma16(ah[mi], bh[ni], acc[mi][ni]);
          acc[mi][ni] = mfma16(ah[mi], bl[ni], acc[mi][ni]);
          acc[mi][ni] = mfma16(al[mi], bh[ni], acc[mi][ni]);
        }
    }
    __syncthreads();
  }
#pragma unroll
  for (int mi = 0; mi < 2; ++mi)
#pragma unroll
    for (int ni = 0; ni < 2; ++ni)
#pragma unroll
      for (int i = 0; i < 4; ++i) {
        int m = m0 + wm * 32 + mi * 16 + kb * 4 + i;
        int n = n0 + wn * 32 + ni * 16 + cl;
        out[(size_t)m * NO + n] = acc[mi][ni][i];
      }
}

extern "C" void kernel_launch(void* const* d_in, const int* in_sizes, int n_in,
                              void* d_out, int out_size, void* d_ws, size_t ws_size,
                              hipStream_t stream) {
  const float* x = (const float*)d_in[0];
  const float* in_proj_w = (const float*)d_in[1];
  const float* conv_w = (const float*)d_in[2];
  const float* conv_b = (const float*)d_in[3];
  const float* x_proj_w = (const float*)d_in[4];
  const float* A_logs = (const float*)d_in[5];
  const float* Ds = (const float*)d_in[6];
  const float* dt_bias = (const float*)d_in[7];
  const float* out_norm_g = (const float*)d_in[8];
  const float* out_norm_b = (const float*)d_in[9];
  const float* out_proj_w = (const float*)d_in[10];
  float* out = (float*)d_out;

  float* ws = (float*)d_ws;
  float* xi_raw = ws;                        // 3145728 f
  float* zg = xi_raw + 3145728;              // 3145728 f
  float* dt_buf = zg + 3145728;              // 393216 f
  float* states = dt_buf + 393216;           // 12582912 f
  float* cdec = states + 12582912;           // 6144 f
  float* ys = cdec + 6144;                   // 12582912 f
  unsigned short* u16p = (unsigned short*)(ys + 12582912);
  unsigned short* xi_hi = u16p;  u16p += 3145728;
  unsigned short* xi_lo = u16p;  u16p += 3145728;
  unsigned short* x_hi = u16p;   u16p += 1572864;
  unsigned short* x_lo = u16p;   u16p += 1572864;
  unsigned short* win_hi = u16p; u16p += 147456;
  unsigned short* win_lo = u16p; u16p += 147456;
  unsigned short* wxp_hi = u16p; u16p += 215040;
  unsigned short* wxp_lo = u16p; u16p += 215040;
  unsigned short* wout_hi = u16p; u16p += 73728;
  unsigned short* wout_lo = u16p; u16p += 73728;
  unsigned short* Bhi = u16p;    u16p += 2097152;
  unsigned short* Blo = u16p;    u16p += 2097152;
  unsigned short* Chi = u16p;    u16p += 2097152;
  unsigned short* Clo = u16p;    u16p += 2097152;
  unsigned short* y2h = (unsigned short*)xi_raw;  // alias: xi_raw dead after conv
  unsigned short* y2l = y2h + 3145728;

  k_cvt<<<(1572864 + 255) / 256, 256, 0, stream>>>(x, x_hi, x_lo, 1572864);
  k_cvt<<<(147456 + 255) / 256, 256, 0, stream>>>(in_proj_w, win_hi, win_lo, 147456);
  k_cvt<<<(215040 + 255) / 256, 256, 0, stream>>>(x_proj_w, wxp_hi, wxp_lo, 215040);
  k_cvt<<<(73728 + 255) / 256, 256, 0, stream>>>(out_proj_w, wout_hi, wout_lo, 73728);

  k_inproj<<<dim3(12, 128), 256, 0, stream>>>(x_hi, x_lo, win_hi, win_lo, xi_raw, zg);
  k_conv<<<dim3(12288), 256, 0, stream>>>(xi_raw, conv_w, conv_b, xi_hi, xi_lo);
  k_xproj<<<dim3(3, 128, 4), 256, 0, stream>>>(xi_hi, xi_lo, wxp_hi, wxp_lo, dt_bias,
                                               dt_buf, Bhi, Blo, Chi, Clo);
  k_states<<<dim3(64, 4, 2), 256, 0, stream>>>(xi_hi, xi_lo, dt_buf, Bhi, Blo, A_logs,
                                               states, cdec);
  k_scan<<<dim3(8, 96), 256, 0, stream>>>(states, cdec);
  k_out<<<dim3(64, 4, 2), 256, 0, stream>>>(xi_hi, xi_lo, dt_buf, Bhi, Blo, Chi, Clo,
                                            A_logs, Ds, states, ys);
  k_ln<<<dim3(8192), 128, 0, stream>>>(ys, zg, out_norm_g, out_norm_b, y2h, y2l);
  k_outproj<<<dim3(3, 128), 256, 0, stream>>>(y2h, y2l, wout_hi, wout_lo, out);
}